// Round 1
// 1884.870 us; speedup vs baseline: 1.1120x; 1.1120x over previous
//
#include <hip/hip_runtime.h>

#define KDIM 50
#define TDIM 40
#define VDIM 30000
#define THDIM 800
#define EHDIM 200
#define EDIM 300
#define BDIM 100
#define DELTAF 0.005f
#define EPSF 1e-6f
#define LOGD (-5.2983174f)
#define MROWS 2560   // TDIM*64 rows for MFMA A operand
#define KPAD 320     // E padded to 320
#define VROWS 30080  // V padded to 235*128
#define VT 80        // v-tile per MFMA block (fallback path)
#define NBLK_V 375   // 30000/80 (fallback path)
#define LBSTR 328    // fallback LDS B-tile row stride
#define GEMM_LDS 81920  // 128 rows * 320 cols * 2B

typedef __attribute__((ext_vector_type(8))) short bf16x8;
typedef __attribute__((ext_vector_type(4))) float f32x4;
typedef unsigned int u32;

__device__ inline float wred64(float v) {
  v += __shfl_xor(v, 32, 64); v += __shfl_xor(v, 16, 64);
  v += __shfl_xor(v, 8, 64);  v += __shfl_xor(v, 4, 64);
  v += __shfl_xor(v, 2, 64);  v += __shfl_xor(v, 1, 64);
  return v;
}

__device__ inline unsigned short f2bf(float f) {
  union { float f; unsigned u; } x; x.f = f;
  unsigned r = x.u + 0x7fffu + ((x.u >> 16) & 1u);
  return (unsigned short)(r >> 16);
}

__device__ inline void gload_lds16(const void* g, void* l) {
  __builtin_amdgcn_global_load_lds(
      (const __attribute__((address_space(1))) u32*)g,
      (__attribute__((address_space(3))) u32*)l, 16, 0, 0);
}

// ---------------- A2 prep: mu_q_alpha[k][t][e] -> bf16 A2[t*64+k][e<320] ----
__global__ void k_prep_A2(const float* __restrict__ mu_q, unsigned short* __restrict__ A2) {
  int idx = blockIdx.x * 256 + threadIdx.x;   // 2560*320 = 819200
  if (idx >= MROWS * KPAD) return;
  int m = idx / KPAD, e = idx % KPAD;
  int t = m >> 6, kp = m & 63;
  float v = 0.f;
  if (kp < KDIM && e < EDIM) v = mu_q[(kp * TDIM + t) * EDIM + e];
  A2[idx] = f2bf(v);
}

// ---------------- B2 prep: word_emb fp32 [30000][300] -> bf16 [30080][320] --
// PRE-SWIZZLED: 16B slot s (e>>3) stored at physical slot s ^ (v&7), so the
// GEMM's linear global_load_lds staging + XOR'd ds_read_b128 is bank-balanced.
__global__ void k_prep_B(const float* __restrict__ we, unsigned short* __restrict__ B2) {
  int idx = blockIdx.x * 256 + threadIdx.x;   // 30080*80 = 2406400
  if (idx >= VROWS * 80) return;
  int v = idx / 80, e4 = (idx % 80) * 4;
  ushort4 o = {0, 0, 0, 0};
  if (v < VDIM && e4 < EDIM) {
    float4 w = *(const float4*)(we + (size_t)v * EDIM + e4);
    o.x = f2bf(w.x); o.y = f2bf(w.y); o.z = f2bf(w.z); o.w = f2bf(w.w);
  }
  int dcol = (((e4 >> 3) ^ (v & 7)) << 3) | (e4 & 7);
  *(ushort4*)(B2 + (size_t)v * KPAD + dcol) = o;
}

// ---------------- out_map = rnn_inp @ W_map^T + b_map  [40,200] -------------
#define MP_VS 96
#define RS_STR 44
#define WS_STR 104
__global__ __launch_bounds__(256) void k_map2(const float* __restrict__ rnn,
                                              const float* __restrict__ Wmap,
                                              const float* __restrict__ bmap,
                                              float* __restrict__ omap) {
  __shared__ __align__(16) float rs[MP_VS * RS_STR];
  __shared__ __align__(16) float wsb[MP_VS * WS_STR];
  int c = blockIdx.x, eh = blockIdx.y;
  int v0 = c * MP_VS, e0 = eh * 100;
  int tid = threadIdx.x;
  for (int idx = tid; idx < TDIM * MP_VS; idx += 256) {
    int t = idx / MP_VS, vv = idx % MP_VS;
    int v = v0 + vv;
    rs[vv * RS_STR + t] = (v < VDIM) ? rnn[(size_t)t * VDIM + v] : 0.f;
  }
  for (int idx = tid; idx < 100 * MP_VS; idx += 256) {
    int e = idx / MP_VS, vv = idx % MP_VS;
    int v = v0 + vv;
    wsb[vv * WS_STR + e] = (v < VDIM) ? Wmap[(size_t)(e0 + e) * VDIM + v] : 0.f;
  }
  __syncthreads();
  if (tid >= 250) return;
  int eg = tid / 10, tg = tid % 10;
  float acc[4][4];
#pragma unroll
  for (int i = 0; i < 4; i++)
#pragma unroll
    for (int j = 0; j < 4; j++) acc[i][j] = 0.f;
  int nvv = min(MP_VS, VDIM - v0);
  for (int vv = 0; vv < nvv; vv++) {
    float4 wv = *(const float4*)&wsb[vv * WS_STR + eg * 4];
    float4 rv = *(const float4*)&rs[vv * RS_STR + tg * 4];
    float wa[4] = {wv.x, wv.y, wv.z, wv.w};
    float ra[4] = {rv.x, rv.y, rv.z, rv.w};
#pragma unroll
    for (int i = 0; i < 4; i++)
#pragma unroll
      for (int j = 0; j < 4; j++) acc[i][j] += wa[i] * ra[j];
  }
#pragma unroll
  for (int i = 0; i < 4; i++) {
    int e = e0 + eg * 4 + i;
#pragma unroll
    for (int j = 0; j < 4; j++) {
      int t = tg * 4 + j;
      float a = acc[i][j];
      if (c == 0) a += bmap[e];
      atomicAdd(&omap[t * EHDIM + e], a);
    }
  }
}

// ---------------- Whh transpose+pack to bf16 pairs: WhhT[l][jp][i] ----------
__global__ void k_wt(const float* __restrict__ Whh, unsigned* __restrict__ WhhT) {
  int l = blockIdx.x / 100, jp = blockIdx.x % 100;
  for (int i = threadIdx.x; i < THDIM; i += 256) {
    float w0 = Whh[(l * THDIM + i) * EHDIM + 2 * jp];
    float w1 = Whh[(l * THDIM + i) * EHDIM + 2 * jp + 1];
    WhhT[(l * 100 + jp) * THDIM + i] = (unsigned)f2bf(w0) | ((unsigned)f2bf(w1) << 16);
  }
}

// ---------------- LSTM input GEMM: G[t][i] = Wih[l][i]·x[t] + bih + bhh -----
__global__ void k_igemm(const float* __restrict__ Wih, const float* __restrict__ bih,
                        const float* __restrict__ bhh, const float* __restrict__ x,
                        float* __restrict__ G, int l) {
  int wave = threadIdx.x >> 6, lane = threadIdx.x & 63;
  int d0 = blockIdx.x * 80 + wave * 20;
  for (int n = 0; n < 20; n++) {
    int d = d0 + n;
    int t = d / THDIM, i = d % THDIM;
    const float* row = Wih + (l * THDIM + i) * EHDIM;
    const float* xt = x + t * EHDIM;
    float acc = 0.f;
#pragma unroll
    for (int m = 0; m < 4; m++) { int j = m * 64 + lane; if (j < EHDIM) acc += row[j] * xt[j]; }
    acc = wred64(acc);
    if (lane == 0) G[t * THDIM + i] = acc + bih[l * THDIM + i] + bhh[l * THDIM + i];
  }
}

// ---------------- LSTM recurrence (single block, streams bf16 WhhT) ---------
__global__ __launch_bounds__(1024) void k_rec(const unsigned* __restrict__ WT,
                                              const float* __restrict__ G,
                                              float* __restrict__ xout) {
  __shared__ __align__(16) float h[EHDIM];
  __shared__ float g[THDIM];
  int tid = threadIdx.x;
  if (tid < EHDIM) h[tid] = 0.f;
  float c = 0.f;
  __syncthreads();
  for (int t = 0; t < TDIM; t++) {
    if (tid < THDIM) {
      float acc = G[t * THDIM + tid];
      const unsigned* wp = WT + tid;
      const float4* h4 = (const float4*)h;
      for (int q = 0; q < 50; q++) {
        float4 hq = h4[q];
        unsigned wa = wp[(2 * q) * THDIM];
        unsigned wb = wp[(2 * q + 1) * THDIM];
        union { unsigned u; float f; } la, ha, lb, hb;
        la.u = wa << 16; ha.u = wa & 0xffff0000u;
        lb.u = wb << 16; hb.u = wb & 0xffff0000u;
        acc += la.f * hq.x + ha.f * hq.y + lb.f * hq.z + hb.f * hq.w;
      }
      g[tid] = acc;
    }
    __syncthreads();
    if (tid < EHDIM) {
      float si = 1.f / (1.f + __expf(-g[tid]));
      float sf = 1.f / (1.f + __expf(-g[200 + tid]));
      float sg = tanhf(g[400 + tid]);
      float so = 1.f / (1.f + __expf(-g[600 + tid]));
      c = sf * c + si * sg;
      float hn = so * tanhf(c);
      xout[t * EHDIM + tid] = hn;
      h[tid] = hn;
    }
    __syncthreads();
  }
}

// ---------------- eta chain (single block, W in LDS) ------------------------
#define WSTR 252
__global__ void k_eta(const float* __restrict__ Wmu, const float* __restrict__ bmu,
                      const float* __restrict__ Wls, const float* __restrict__ bls,
                      const float* __restrict__ lout, float* __restrict__ etas,
                      float* __restrict__ scal) {
  __shared__ __align__(16) float Wm[KDIM * WSTR + 4];
  __shared__ __align__(16) float Wl[KDIM * WSTR + 4];
  __shared__ __align__(16) float inp[256];
  __shared__ float mu_s[KDIM], ls_s[KDIM];
  int tid = threadIdx.x;  // 512
  for (int i = tid; i < KDIM * WSTR; i += 512) {
    int r = i / WSTR, c2 = i % WSTR;
    Wm[i] = (c2 < 250) ? Wmu[r * 250 + c2] : 0.f;
    Wl[i] = (c2 < 250) ? Wls[r * 250 + c2] : 0.f;
  }
  if (tid < 4) { Wm[KDIM * WSTR + tid] = 0.f; Wl[KDIM * WSTR + tid] = 0.f; }
  for (int i = tid; i < 256; i += 512) inp[i] = 0.f;
  __syncthreads();
  int wave = tid >> 6, lane = tid & 63;
  float kl = 0.f;
  for (int t = 0; t < TDIM; t++) {
    if (tid < EHDIM) inp[tid] = lout[t * EHDIM + tid];
    __syncthreads();
    float4 x4 = ((const float4*)inp)[lane];
    for (int jb = wave; jb < 2 * KDIM; jb += 8) {
      const float* Wrow = (jb < KDIM) ? (Wm + jb * WSTR) : (Wl + (jb - KDIM) * WSTR);
      float4 w4 = ((const float4*)Wrow)[lane];
      float acc = w4.x * x4.x + w4.y * x4.y + w4.z * x4.z + w4.w * x4.w;
      acc = wred64(acc);
      if (lane == 0) {
        if (jb < KDIM) mu_s[jb] = acc + bmu[jb];
        else ls_s[jb - KDIM] = acc + bls[jb - KDIM];
      }
    }
    __syncthreads();
    if (tid < 64) {
      float v = 0.f;
      if (tid < KDIM) {
        float m = mu_s[tid], ls = ls_s[tid];
        float ep = inp[EHDIM + tid];
        float d = m - ep;
        if (t == 0) v = 0.5f * ((__expf(ls) + d * d) / (1.f + EPSF) - 1.f - ls);
        else        v = 0.5f * ((__expf(ls) + d * d) / (DELTAF + EPSF) - 1.f + LOGD - ls);
        etas[t * KDIM + tid] = m;
      }
      v = wred64(v);
      if (tid == 0) kl += v;
    }
    __syncthreads();
    if (tid < KDIM) inp[EHDIM + tid] = mu_s[tid];
    __syncthreads();
  }
  if (tid == 0) scal[2] = kl;
}

// ---------------- h_pre = nb @ W_theta[:, :V]^T  (fp32 tiled, split-K) ------
#define HP_BK 32
#define HP_STRIDE 132
__global__ __launch_bounds__(256, 2) void k_hpre(const float* __restrict__ nb,
                                                 const float* __restrict__ Wth,
                                                 float* __restrict__ h_pre) {
  __shared__ __align__(16) float As[HP_BK * HP_STRIDE];
  __shared__ __align__(16) float Bs[HP_BK * HP_STRIDE];
  int tid = threadIdx.x;
  int nt = blockIdx.x, zc = blockIdx.y;
  int kt0 = zc * 20, ktend = min(938, kt0 + 20);
  float acc[8][8];
#pragma unroll
  for (int i = 0; i < 8; i++)
#pragma unroll
    for (int j = 0; j < 8; j++) acc[i][j] = 0.f;
  int tx = tid & 15, ty = tid >> 4;
  for (int kt = kt0; kt < ktend; kt++) {
    int v0 = kt * HP_BK;
#pragma unroll
    for (int r = 0; r < 4; r++) {
      int j = tid + r * 256;
      int row = j >> 3, c4 = (j & 7) * 4;
      int v = v0 + c4;
      float4 val = {0.f, 0.f, 0.f, 0.f};
      if (row < BDIM) {
        const float* base = nb + (size_t)row * VDIM + v;
        if (v + 3 < VDIM) val = *(const float4*)base;
        else {
          if (v < VDIM) val.x = base[0];
          if (v + 1 < VDIM) val.y = base[1];
          if (v + 2 < VDIM) val.z = base[2];
        }
      }
      As[(c4 + 0) * HP_STRIDE + row] = val.x;
      As[(c4 + 1) * HP_STRIDE + row] = val.y;
      As[(c4 + 2) * HP_STRIDE + row] = val.z;
      As[(c4 + 3) * HP_STRIDE + row] = val.w;
    }
#pragma unroll
    for (int r = 0; r < 4; r++) {
      int j = tid + r * 256;
      int row = j >> 3, c4 = (j & 7) * 4;
      int th = nt * 128 + row;
      int v = v0 + c4;
      float4 val = {0.f, 0.f, 0.f, 0.f};
      if (th < THDIM) {
        const float* base = Wth + (size_t)th * 30050 + v;
        if (v + 3 < VDIM) {
          float2 p0 = *(const float2*)base;
          float2 p1 = *(const float2*)(base + 2);
          val.x = p0.x; val.y = p0.y; val.z = p1.x; val.w = p1.y;
        } else {
          if (v < VDIM) val.x = base[0];
          if (v + 1 < VDIM) val.y = base[1];
          if (v + 2 < VDIM) val.z = base[2];
        }
      }
      Bs[(c4 + 0) * HP_STRIDE + row] = val.x;
      Bs[(c4 + 1) * HP_STRIDE + row] = val.y;
      Bs[(c4 + 2) * HP_STRIDE + row] = val.z;
      Bs[(c4 + 3) * HP_STRIDE + row] = val.w;
    }
    __syncthreads();
#pragma unroll
    for (int k = 0; k < HP_BK; k++) {
      float4 a0 = *(const float4*)&As[k * HP_STRIDE + ty * 8];
      float4 a1 = *(const float4*)&As[k * HP_STRIDE + ty * 8 + 4];
      float4 b0 = *(const float4*)&Bs[k * HP_STRIDE + tx * 8];
      float4 b1 = *(const float4*)&Bs[k * HP_STRIDE + tx * 8 + 4];
      float a[8] = {a0.x, a0.y, a0.z, a0.w, a1.x, a1.y, a1.z, a1.w};
      float b[8] = {b0.x, b0.y, b0.z, b0.w, b1.x, b1.y, b1.z, b1.w};
#pragma unroll
      for (int i = 0; i < 8; i++)
#pragma unroll
        for (int j = 0; j < 8; j++) acc[i][j] += a[i] * b[j];
    }
    __syncthreads();
  }
#pragma unroll
  for (int i = 0; i < 8; i++) {
    int bb = ty * 8 + i;
    if (bb >= BDIM) continue;
#pragma unroll
    for (int j = 0; j < 8; j++) {
      int th = nt * 128 + tx * 8 + j;
      if (th < THDIM) atomicAdd(&h_pre[bb * THDIM + th], acc[i][j]);
    }
  }
}

// ---------------- theta path: tanh, softmax, kl_theta -----------------------
__global__ void k_theta(const float* __restrict__ hpre, const float* __restrict__ bth,
                        const float* __restrict__ Wth, const float* __restrict__ Wmt,
                        const float* __restrict__ bmt, const float* __restrict__ Wlt,
                        const float* __restrict__ blt, const float* __restrict__ etas,
                        const int* __restrict__ times, float* __restrict__ theta,
                        float* __restrict__ scal) {
  __shared__ float et[KDIM];
  __shared__ float hl[THDIM];
  __shared__ float mu_s[KDIM], ls_s[KDIM];
  int b = blockIdx.x, tid = threadIdx.x;
  if (tid < KDIM) et[tid] = etas[times[b] * KDIM + tid];
  __syncthreads();
  for (int th = tid; th < THDIM; th += 256) {
    float acc = hpre[b * THDIM + th] + bth[th];
    const float* wrow = Wth + (size_t)th * 30050 + VDIM;
#pragma unroll 10
    for (int k = 0; k < KDIM; k++) acc += et[k] * wrow[k];
    hl[th] = tanhf(acc);
  }
  __syncthreads();
  int wave = tid >> 6, lane = tid & 63;
  for (int jb = wave; jb < 2 * KDIM; jb += 4) {
    const float* row = (jb < KDIM) ? (Wmt + jb * THDIM) : (Wlt + (jb - KDIM) * THDIM);
    float acc = 0.f;
#pragma unroll
    for (int m = 0; m < 13; m++) { int j = m * 64 + lane; if (j < THDIM) acc += row[j] * hl[j]; }
    acc = wred64(acc);
    if (lane == 0) {
      if (jb < KDIM) mu_s[jb] = acc + bmt[jb];
      else ls_s[jb - KDIM] = acc + blt[jb - KDIM];
    }
  }
  __syncthreads();
  if (tid < 64) {
    float m = (tid < KDIM) ? mu_s[tid] : -1e30f;
    float mx = m;
#pragma unroll
    for (int o = 32; o >= 1; o >>= 1) mx = fmaxf(mx, __shfl_xor(mx, o, 64));
    float e = (tid < KDIM) ? __expf(m - mx) : 0.f;
    float s = wred64(e);
    if (tid < KDIM) theta[b * KDIM + tid] = e / s;
    float v = 0.f;
    if (tid < KDIM) {
      float ls = ls_s[tid];
      float d = mu_s[tid] - et[tid];
      v = 0.5f * ((__expf(ls) + d * d) / (1.f + EPSF) - 1.f - ls);
    }
    v = wred64(v);
    if (tid == 0) atomicAdd(&scal[3], v);
  }
}

// ---------------- kl_alpha ---------------------------------------------------
__global__ void k_klalpha(const float* __restrict__ mu, const float* __restrict__ ls,
                          float* __restrict__ scal) {
  int idx = blockIdx.x * 256 + threadIdx.x;
  float v = 0.f;
  if (idx < KDIM * TDIM * EDIM) {
    int t = (idx / EDIM) % TDIM;
    float l = ls[idx], m = mu[idx];
    if (t == 0) v = 0.5f * ((__expf(l) + m * m) / (1.f + EPSF) - 1.f - l);
    else { float d = m - mu[idx - EDIM]; v = 0.5f * ((__expf(l) + d * d) / (DELTAF + EPSF) - 1.f + LOGD - l); }
  }
  v = wred64(v);
  __shared__ float p[4];
  if ((threadIdx.x & 63) == 0) p[threadIdx.x >> 6] = v;
  __syncthreads();
  if (threadIdx.x == 0) atomicAdd(&scal[1], p[0] + p[1] + p[2] + p[3]);
}

// ---------------- time buckets ----------------------------------------------
__global__ void k_bucket(const int* __restrict__ times, int* __restrict__ bcnt,
                         int* __restrict__ bucket) {
  __shared__ int cnt[TDIM];
  int tid = threadIdx.x;  // 128
  if (tid < TDIM) cnt[tid] = 0;
  __syncthreads();
  if (tid < BDIM) {
    int t = times[tid];
    int s = atomicAdd(&cnt[t], 1);
    bucket[t * 128 + s] = tid;
  }
  __syncthreads();
  if (tid < TDIM) bcnt[tid] = cnt[tid];
}

// ---------------- wgt[b][k] = theta[b][k] / Z[t_b*64+k] ---------------------
__global__ void k_wgt(const float* __restrict__ theta, const float* __restrict__ Z,
                      const int* __restrict__ times, float* __restrict__ wgt) {
  int idx = blockIdx.x * 256 + threadIdx.x;  // 6400
  if (idx >= BDIM * 64) return;
  int b = idx >> 6, k = idx & 63;
  float v = 0.f;
  if (k < KDIM) v = theta[b * KDIM + k] / Z[times[b] * 64 + k];
  wgt[idx] = v;
}

// ================= B-stationary MFMA GEMM (both passes) =====================
// One block per 128-v-col tile (grid=235, 512 thr = 8 waves). The block's full
// K=320 B panel (80 KB, pre-swizzled B2) is staged to dynamic LDS ONCE via
// linear global_load_lds; the main loop over all 40 t-quads is barrier-free,
// reading A fragments straight from L2-resident A2 (1.6 MB) and B fragments
// from LDS with the matching XOR slot swizzle (2-way max bank aliasing).
template <bool PASSB>
__global__ __launch_bounds__(512, 2) void k_gemm(
    const unsigned short* __restrict__ A2, const unsigned short* __restrict__ B2,
    float* __restrict__ Z, const float* __restrict__ wgt,
    const float* __restrict__ bows, const int* __restrict__ bcnt,
    const int* __restrict__ bucket, float* __restrict__ scal) {
  extern __shared__ __align__(16) unsigned short Bs[];  // [128][320] swizzled
  __shared__ float p[8];
  int tid = threadIdx.x, wv = tid >> 6, lane = tid & 63;
  int vbase = blockIdx.x * 128;
  int r15 = lane & 15, gh = lane >> 4, x7 = r15 & 7;

  // ---- stage 80 KB linearly: 80 chunks of 1 KB, 10 per wave
  const unsigned short* gB = B2 + (size_t)vbase * KPAD;
#pragma unroll
  for (int c = 0; c < 10; ++c) {
    int chunk = wv * 10 + c;
    gload_lds16(gB + chunk * 512 + lane * 8, Bs + chunk * 512);
  }
  __syncthreads();

  const unsigned short* Br = Bs + r15 * KPAD;
  float nacc = 0.f;

  for (int jj = 0; jj < 5; ++jj) {
    int q = jj * 8 + wv;  // t-quad owned by this wave this round
    f32x4 acc[4][8];
#pragma unroll
    for (int si = 0; si < 4; ++si)
#pragma unroll
      for (int sj = 0; sj < 8; ++sj) acc[si][sj] = (f32x4){0.f, 0.f, 0.f, 0.f};

    const bf16x8* ab = (const bf16x8*)(A2 + (size_t)(q * 64 + r15) * KPAD) + gh;
#pragma unroll 2
    for (int kk = 0; kk < 10; ++kk) {
      bf16x8 a0 = ab[kk * 4];
      bf16x8 a1 = ab[640 + kk * 4];
      bf16x8 a2 = ab[1280 + kk * 4];
      bf16x8 a3 = ab[1920 + kk * 4];
      int spo = (((kk * 4 + gh) ^ x7) << 3);
#pragma unroll
      for (int sj = 0; sj < 8; ++sj) {
        bf16x8 b = *(const bf16x8*)(Br + sj * 5120 + spo);
        acc[0][sj] = __builtin_amdgcn_mfma_f32_16x16x32_bf16(a0, b, acc[0][sj], 0, 0, 0);
        acc[1][sj] = __builtin_amdgcn_mfma_f32_16x16x32_bf16(a1, b, acc[1][sj], 0, 0, 0);
        acc[2][sj] = __builtin_amdgcn_mfma_f32_16x16x32_bf16(a2, b, acc[2][sj], 0, 0, 0);
        acc[3][sj] = __builtin_amdgcn_mfma_f32_16x16x32_bf16(a3, b, acc[3][sj], 0, 0, 0);
      }
    }

    if (!PASSB) {
      // Z[m] += sum_v exp(logit)
#pragma unroll
      for (int si = 0; si < 4; ++si) {
#pragma unroll
        for (int r = 0; r < 4; ++r) {
          float es = 0.f;
#pragma unroll
          for (int sj = 0; sj < 8; ++sj) {
            int v = vbase + sj * 16 + r15;
            es += (v < VDIM) ? __expf(acc[si][sj][r]) : 0.f;
          }
          es += __shfl_xor(es, 1, 64); es += __shfl_xor(es, 2, 64);
          es += __shfl_xor(es, 4, 64); es += __shfl_xor(es, 8, 64);
          if (r15 == 0) atomicAdd(&Z[q * 64 + si * 16 + gh * 4 + r], es);
        }
      }
    } else {
#pragma unroll
      for (int si = 0; si < 4; ++si)
#pragma unroll
        for (int sj = 0; sj < 8; ++sj)
#pragma unroll
          for (int r = 0; r < 4; ++r) acc[si][sj][r] = __expf(acc[si][sj][r]);
      int cnt = bcnt[q];
      for (int n = 0; n < cnt; ++n) {
        int b = bucket[q * 128 + n];
        float4 w4[4];
#pragma unroll
        for (int si = 0; si < 4; ++si)
          w4[si] = *(const float4*)(wgt + b * 64 + si * 16 + gh * 4);
#pragma unroll
        for (int sj = 0; sj < 8; ++sj) {
          float local = 0.f;
#pragma unroll
          for (int si = 0; si < 4; ++si)
            local += w4[si].x * acc[si][sj][0] + w4[si].y * acc[si][sj][1] +
                     w4[si].z * acc[si][sj][2] + w4[si].w * acc[si][sj][3];
          local += __shfl_xor(local, 16, 64);
          local += __shfl_xor(local, 32, 64);
          int v = vbase + sj * 16 + r15;
          if (lane < 16 && v < VDIM)
            nacc += bows[(size_t)b * VDIM + v] * __logf(local + EPSF);
        }
      }
    }
  }

  if (PASSB) {
    nacc = wred64(nacc);
    if (lane == 0) p[wv] = nacc;
    __syncthreads();
    if (tid == 0)
      atomicAdd(&scal[0], p[0] + p[1] + p[2] + p[3] + p[4] + p[5] + p[6] + p[7]);
  }
}

// ================= fallback-path MFMA kernels (round-1, known-good) =========
__device__ inline void stage_B(const float* __restrict__ we, int vbase,
                               unsigned short* LB, int tid) {
  for (int q = tid; q < VT * 75; q += 256) {
    int vp = q / 75, e4 = (q % 75) * 4;
    float4 w = *(const float4*)(we + (size_t)(vbase + vp) * EDIM + e4);
    unsigned* p32 = (unsigned*)(LB + vp * LBSTR + e4);
    p32[0] = (unsigned)f2bf(w.x) | ((unsigned)f2bf(w.y) << 16);
    p32[1] = (unsigned)f2bf(w.z) | ((unsigned)f2bf(w.w) << 16);
  }
  for (int q = tid; q < VT * 28; q += 256) {
    int vp = q / 28, e = 300 + q % 28;
    LB[vp * LBSTR + e] = 0;
  }
}

__device__ inline void quad_mainloop(const unsigned short* __restrict__ A2,
                                     const unsigned short* LB, int quad, int lane,
                                     f32x4 (&acc)[4][5]) {
  int mrow = quad * 64 + (lane & 15);
  int eoff = (lane >> 4) * 8;
  const bf16x8* ap[4];
#pragma unroll
  for (int ss = 0; ss < 4; ss++)
    ap[ss] = (const bf16x8*)(A2 + (size_t)(mrow + ss * 16) * KPAD + eoff);
  const unsigned short* bp = LB + (lane & 15) * LBSTR + eoff;
#pragma unroll
  for (int kk = 0; kk < 10; kk++) {
    bf16x8 a[4];
#pragma unroll
    for (int ss = 0; ss < 4; ss++) a[ss] = ap[ss][kk * 4];
#pragma unroll
    for (int cf = 0; cf < 5; cf++) {
      bf16x8 b = *(const bf16x8*)(bp + cf * 16 * LBSTR + kk * 32);
#pragma unroll
      for (int ss = 0; ss < 4; ss++)
        acc[ss][cf] = __builtin_amdgcn_mfma_f32_16x16x32_bf16(a[ss], b, acc[ss][cf], 0, 0, 0);
    }
  }
}

__global__ __launch_bounds__(256, 2) void k_passA(const float* __restrict__ we,
                                                  const unsigned short* __restrict__ A2,
                                                  float* __restrict__ Z) {
  __shared__ __align__(16) unsigned short LB[VT * LBSTR];
  int tid = threadIdx.x, vbase = blockIdx.x * VT;
  stage_B(we, vbase, LB, tid);
  __syncthreads();
  int wave = tid >> 6, lane = tid & 63;
  for (int q = wave; q < TDIM; q += 4) {
    f32x4 acc[4][5];
#pragma unroll
    for (int ss = 0; ss < 4; ss++)
#pragma unroll
      for (int cf = 0; cf < 5; cf++) acc[ss][cf] = (f32x4){0.f, 0.f, 0.f, 0.f};
    quad_mainloop(A2, LB, q, lane, acc);
#pragma unroll
    for (int ss = 0; ss < 4; ss++) {
#pragma unroll
      for (int r = 0; r < 4; r++) {
        float s = __expf(acc[ss][0][r]) + __expf(acc[ss][1][r]) + __expf(acc[ss][2][r]) +
                  __expf(acc[ss][3][r]) + __expf(acc[ss][4][r]);
        s += __shfl_xor(s, 1, 64); s += __shfl_xor(s, 2, 64);
        s += __shfl_xor(s, 4, 64); s += __shfl_xor(s, 8, 64);
        if ((lane & 15) == 0)
          atomicAdd(&Z[q * 64 + ss * 16 + (lane >> 4) * 4 + r], s);
      }
    }
  }
}

__global__ __launch_bounds__(256, 2) void k_passB(const float* __restrict__ we,
                                                  const unsigned short* __restrict__ A2,
                                                  const float* __restrict__ wgt,
                                                  const float* __restrict__ bows,
                                                  const int* __restrict__ bcnt,
                                                  const int* __restrict__ bucket,
                                                  float* __restrict__ scal) {
  __shared__ __align__(16) unsigned short LB[VT * LBSTR];
  int tid = threadIdx.x, vbase = blockIdx.x * VT;
  stage_B(we, vbase, LB, tid);
  __syncthreads();
  int wave = tid >> 6, lane = tid & 63;
  float nacc = 0.f;
  for (int t = wave; t < TDIM; t += 4) {
    f32x4 acc[4][5];
#pragma unroll
    for (int ss = 0; ss < 4; ss++)
#pragma unroll
      for (int cf = 0; cf < 5; cf++) acc[ss][cf] = (f32x4){0.f, 0.f, 0.f, 0.f};
    quad_mainloop(A2, LB, t, lane, acc);
#pragma unroll
    for (int ss = 0; ss < 4; ss++)
#pragma unroll
      for (int cf = 0; cf < 5; cf++)
#pragma unroll
        for (int r = 0; r < 4; r++) acc[ss][cf][r] = __expf(acc[ss][cf][r]);
    int cnt = bcnt[t];
    for (int n = 0; n < cnt; n++) {
      int b = bucket[t * 128 + n];
      float4 w[4];
#pragma unroll
      for (int ss = 0; ss < 4; ss++)
        w[ss] = *(const float4*)(wgt + b * 64 + ss * 16 + (lane >> 4) * 4);
#pragma unroll
      for (int cf = 0; cf < 5; cf++) {
        float local = 0.f;
#pragma unroll
        for (int ss = 0; ss < 4; ss++)
          local += w[ss].x * acc[ss][cf][0] + w[ss].y * acc[ss][cf][1] +
                   w[ss].z * acc[ss][cf][2] + w[ss].w * acc[ss][cf][3];
        local += __shfl_xor(local, 16, 64);
        local += __shfl_xor(local, 32, 64);
        int v = vbase + cf * 16 + (lane & 15);
        float contrib = bows[(size_t)b * VDIM + v] * __logf(local + EPSF);
        if (lane < 16) nacc += contrib;
      }
    }
  }
  nacc = wred64(nacc);
  __shared__ float p[4];
  if (lane == 0) p[wave] = nacc;
  __syncthreads();
  if (tid == 0) atomicAdd(&scal[0], p[0] + p[1] + p[2] + p[3]);
}

// ---------------- finalize ---------------------------------------------------
__global__ void k_finalize(const float* __restrict__ scal, float* __restrict__ out) {
  if (threadIdx.x == 0 && blockIdx.x == 0) {
    float nll = -scal[0];
    out[0] = nll + scal[1] + scal[2] + scal[3];
    out[1] = nll;
    out[2] = scal[1];
    out[3] = scal[2];
    out[4] = scal[3];
  }
}

extern "C" void kernel_launch(void* const* d_in, const int* in_sizes, int n_in,
                              void* d_out, int out_size, void* d_ws, size_t ws_size,
                              hipStream_t stream) {
  const float* bows  = (const float*)d_in[0];
  const float* nbows = (const float*)d_in[1];
  const float* rnn   = (const float*)d_in[2];
  const float* wemb  = (const float*)d_in[3];
  const float* mua   = (const float*)d_in[4];
  const float* lsa   = (const float*)d_in[5];
  const float* Wth   = (const float*)d_in[6];
  const float* bth   = (const float*)d_in[7];
  const float* Wmt   = (const float*)d_in[8];
  const float* bmt   = (const float*)d_in[9];
  const float* Wlt   = (const float*)d_in[10];
  const float* blt   = (const float*)d_in[11];
  const float* Wmap  = (const float*)d_in[12];
  const float* bmap  = (const float*)d_in[13];
  const float* Wih   = (const float*)d_in[14];
  const float* Whh   = (const float*)d_in[15];
  const float* bihp  = (const float*)d_in[16];
  const float* bhhp  = (const float*)d_in[17];
  const float* Wme   = (const float*)d_in[18];
  const float* bme   = (const float*)d_in[19];
  const float* Wle   = (const float*)d_in[20];
  const float* ble   = (const float*)d_in[21];
  const int* times   = (const int*)d_in[22];

  float* ws = (float*)d_ws;
  float* scal  = ws;                 // 8
  float* Z     = ws + 8;             // 2560
  float* hpre  = ws + 2568;          // 80000
  float* omap  = ws + 82568;         // 8000   (end of zeroed region: 90568 floats)
  float* xa    = ws + 90568;         // 8000
  float* xb    = ws + 98568;         // 8000
  float* lout  = ws + 106568;        // 8000
  float* Gin   = ws + 114568;        // 32000
  unsigned* WhhT = (unsigned*)(ws + 146568);   // 240000
  float* etas  = ws + 386568;        // 2000
  float* theta = ws + 388568;        // 5000
  float* wgt   = ws + 393568;        // 6400
  int* bcnt    = (int*)(ws + 399968);          // 64
  int* bucket  = (int*)(ws + 400032);          // 5120
  unsigned short* A2 = (unsigned short*)(ws + 405152);  // 819200 ushorts -> ends 814752
  unsigned short* B2 = (unsigned short*)(ws + 814752);  // 30080*320 ushorts = 19.25 MB

  // fast path needs ws up to byte offset 814752*4 + 19251200 = 22510208
  bool fast = ws_size >= 23000000u;

  if (fast) {
    static bool attr_set = false;
    if (!attr_set) {
      auto kA = k_gemm<false>;
      auto kB = k_gemm<true>;
      (void)hipFuncSetAttribute((const void*)kA,
                                hipFuncAttributeMaxDynamicSharedMemorySize, GEMM_LDS);
      (void)hipFuncSetAttribute((const void*)kB,
                                hipFuncAttributeMaxDynamicSharedMemorySize, GEMM_LDS);
      attr_set = true;
    }
  }

  hipMemsetAsync(ws, 0, 90568 * sizeof(float), stream);

  k_prep_A2<<<3200, 256, 0, stream>>>(mua, A2);
  if (fast) k_prep_B<<<9400, 256, 0, stream>>>(wemb, B2);
  k_map2<<<dim3(313, 2), 256, 0, stream>>>(rnn, Wmap, bmap, omap);
  k_wt<<<300, 256, 0, stream>>>(Whh, WhhT);
  k_bucket<<<1, 128, 0, stream>>>(times, bcnt, bucket);

  if (fast)
    k_gemm<false><<<235, 512, GEMM_LDS, stream>>>(A2, B2, Z, nullptr, nullptr,
                                                  nullptr, nullptr, nullptr);
  else
    k_passA<<<NBLK_V, 256, 0, stream>>>(wemb, A2, Z);

  k_igemm<<<400, 256, 0, stream>>>(Wih, bihp, bhhp, omap, Gin, 0);
  k_rec<<<1, 1024, 0, stream>>>(WhhT, Gin, xa);
  k_igemm<<<400, 256, 0, stream>>>(Wih, bihp, bhhp, xa, Gin, 1);
  k_rec<<<1, 1024, 0, stream>>>(WhhT + 100 * 800, Gin, xb);
  k_igemm<<<400, 256, 0, stream>>>(Wih, bihp, bhhp, xb, Gin, 2);
  k_rec<<<1, 1024, 0, stream>>>(WhhT + 200 * 800, Gin, lout);

  k_eta<<<1, 512, 0, stream>>>(Wme, bme, Wle, ble, lout, etas, scal);
  k_hpre<<<dim3(7, 47), 256, 0, stream>>>(nbows, Wth, hpre);
  k_theta<<<100, 256, 0, stream>>>(hpre, bth, Wth, Wmt, bmt, Wlt, blt, etas, times, theta, scal);
  k_wgt<<<25, 256, 0, stream>>>(theta, Z, times, wgt);
  k_klalpha<<<2344, 256, 0, stream>>>(mua, lsa, scal);

  if (fast)
    k_gemm<true><<<235, 512, GEMM_LDS, stream>>>(A2, B2, Z, wgt, bows, bcnt,
                                                 bucket, scal);
  else
    k_passB<<<NBLK_V, 256, 0, stream>>>(wemb, A2, wgt, bows, bcnt, bucket, scal);

  k_finalize<<<1, 64, 0, stream>>>(scal, (float*)d_out);
}

// Round 3
// 1838.313 us; speedup vs baseline: 1.1401x; 1.0253x over previous
//
#include <hip/hip_runtime.h>

#define KDIM 50
#define TDIM 40
#define VDIM 30000
#define THDIM 800
#define EHDIM 200
#define EDIM 300
#define BDIM 100
#define DELTAF 0.005f
#define EPSF 1e-6f
#define LOGD (-5.2983174f)
#define MROWS 2560   // TDIM*64 rows for MFMA A operand
#define KPAD 320     // E padded to 320
#define VROWS 30080  // V padded to 235*128
#define VT 80        // v-tile per MFMA block (fallback path)
#define NBLK_V 375   // 30000/80 (fallback path)
#define LBSTR 328    // fallback LDS B-tile row stride
#define GEMM_LDS 81920  // 128 rows * 320 cols * 2B

typedef __attribute__((ext_vector_type(8))) short bf16x8;
typedef __attribute__((ext_vector_type(4))) float f32x4;
typedef unsigned int u32;

__device__ inline float wred64(float v) {
  v += __shfl_xor(v, 32, 64); v += __shfl_xor(v, 16, 64);
  v += __shfl_xor(v, 8, 64);  v += __shfl_xor(v, 4, 64);
  v += __shfl_xor(v, 2, 64);  v += __shfl_xor(v, 1, 64);
  return v;
}

__device__ inline unsigned short f2bf(float f) {
  union { float f; unsigned u; } x; x.f = f;
  unsigned r = x.u + 0x7fffu + ((x.u >> 16) & 1u);
  return (unsigned short)(r >> 16);
}

__device__ inline void gload_lds16(const void* g, void* l) {
  __builtin_amdgcn_global_load_lds(
      (const __attribute__((address_space(1))) u32*)g,
      (__attribute__((address_space(3))) u32*)l, 16, 0, 0);
}

// ---------------- A2 prep: mu_q_alpha[k][t][e] -> bf16 A2[t*64+k][e<320] ----
__global__ void k_prep_A2(const float* __restrict__ mu_q, unsigned short* __restrict__ A2) {
  int idx = blockIdx.x * 256 + threadIdx.x;   // 2560*320 = 819200
  if (idx >= MROWS * KPAD) return;
  int m = idx / KPAD, e = idx % KPAD;
  int t = m >> 6, kp = m & 63;
  float v = 0.f;
  if (kp < KDIM && e < EDIM) v = mu_q[(kp * TDIM + t) * EDIM + e];
  A2[idx] = f2bf(v);
}

// ---------------- B2 prep: word_emb fp32 [30000][300] -> bf16 [30080][320] --
// PRE-SWIZZLED: 16B slot s (e>>3) stored at physical slot s ^ (v&7), so the
// GEMM's linear global_load_lds staging + XOR'd ds_read_b128 is bank-balanced.
__global__ void k_prep_B(const float* __restrict__ we, unsigned short* __restrict__ B2) {
  int idx = blockIdx.x * 256 + threadIdx.x;   // 30080*80 = 2406400
  if (idx >= VROWS * 80) return;
  int v = idx / 80, e4 = (idx % 80) * 4;
  ushort4 o = {0, 0, 0, 0};
  if (v < VDIM && e4 < EDIM) {
    float4 w = *(const float4*)(we + (size_t)v * EDIM + e4);
    o.x = f2bf(w.x); o.y = f2bf(w.y); o.z = f2bf(w.z); o.w = f2bf(w.w);
  }
  int dcol = (((e4 >> 3) ^ (v & 7)) << 3) | (e4 & 7);
  *(ushort4*)(B2 + (size_t)v * KPAD + dcol) = o;
}

// ---------------- out_map = rnn_inp @ W_map^T + b_map  [40,200] -------------
#define MP_VS 96
#define RS_STR 44
#define WS_STR 104
__global__ __launch_bounds__(256) void k_map2(const float* __restrict__ rnn,
                                              const float* __restrict__ Wmap,
                                              const float* __restrict__ bmap,
                                              float* __restrict__ omap) {
  __shared__ __align__(16) float rs[MP_VS * RS_STR];
  __shared__ __align__(16) float wsb[MP_VS * WS_STR];
  int c = blockIdx.x, eh = blockIdx.y;
  int v0 = c * MP_VS, e0 = eh * 100;
  int tid = threadIdx.x;
  for (int idx = tid; idx < TDIM * MP_VS; idx += 256) {
    int t = idx / MP_VS, vv = idx % MP_VS;
    int v = v0 + vv;
    rs[vv * RS_STR + t] = (v < VDIM) ? rnn[(size_t)t * VDIM + v] : 0.f;
  }
  for (int idx = tid; idx < 100 * MP_VS; idx += 256) {
    int e = idx / MP_VS, vv = idx % MP_VS;
    int v = v0 + vv;
    wsb[vv * WS_STR + e] = (v < VDIM) ? Wmap[(size_t)(e0 + e) * VDIM + v] : 0.f;
  }
  __syncthreads();
  if (tid >= 250) return;
  int eg = tid / 10, tg = tid % 10;
  float acc[4][4];
#pragma unroll
  for (int i = 0; i < 4; i++)
#pragma unroll
    for (int j = 0; j < 4; j++) acc[i][j] = 0.f;
  int nvv = min(MP_VS, VDIM - v0);
  for (int vv = 0; vv < nvv; vv++) {
    float4 wv = *(const float4*)&wsb[vv * WS_STR + eg * 4];
    float4 rv = *(const float4*)&rs[vv * RS_STR + tg * 4];
    float wa[4] = {wv.x, wv.y, wv.z, wv.w};
    float ra[4] = {rv.x, rv.y, rv.z, rv.w};
#pragma unroll
    for (int i = 0; i < 4; i++)
#pragma unroll
      for (int j = 0; j < 4; j++) acc[i][j] += wa[i] * ra[j];
  }
#pragma unroll
  for (int i = 0; i < 4; i++) {
    int e = e0 + eg * 4 + i;
#pragma unroll
    for (int j = 0; j < 4; j++) {
      int t = tg * 4 + j;
      float a = acc[i][j];
      if (c == 0) a += bmap[e];
      atomicAdd(&omap[t * EHDIM + e], a);
    }
  }
}

// ---------------- Whh transpose+pack to bf16 pairs: WhhT[l][jp][i] ----------
__global__ void k_wt(const float* __restrict__ Whh, unsigned* __restrict__ WhhT) {
  int l = blockIdx.x / 100, jp = blockIdx.x % 100;
  for (int i = threadIdx.x; i < THDIM; i += 256) {
    float w0 = Whh[(l * THDIM + i) * EHDIM + 2 * jp];
    float w1 = Whh[(l * THDIM + i) * EHDIM + 2 * jp + 1];
    WhhT[(l * 100 + jp) * THDIM + i] = (unsigned)f2bf(w0) | ((unsigned)f2bf(w1) << 16);
  }
}

// ---------------- LSTM input GEMM: G[t][i] = Wih[l][i]·x[t] + bih + bhh -----
__global__ void k_igemm(const float* __restrict__ Wih, const float* __restrict__ bih,
                        const float* __restrict__ bhh, const float* __restrict__ x,
                        float* __restrict__ G, int l) {
  int wave = threadIdx.x >> 6, lane = threadIdx.x & 63;
  int d0 = blockIdx.x * 80 + wave * 20;
  for (int n = 0; n < 20; n++) {
    int d = d0 + n;
    int t = d / THDIM, i = d % THDIM;
    const float* row = Wih + (l * THDIM + i) * EHDIM;
    const float* xt = x + t * EHDIM;
    float acc = 0.f;
#pragma unroll
    for (int m = 0; m < 4; m++) { int j = m * 64 + lane; if (j < EHDIM) acc += row[j] * xt[j]; }
    acc = wred64(acc);
    if (lane == 0) G[t * THDIM + i] = acc + bih[l * THDIM + i] + bhh[l * THDIM + i];
  }
}

// ---------------- LSTM recurrence (single block, streams bf16 WhhT) ---------
__global__ __launch_bounds__(1024) void k_rec(const unsigned* __restrict__ WT,
                                              const float* __restrict__ G,
                                              float* __restrict__ xout) {
  __shared__ __align__(16) float h[EHDIM];
  __shared__ float g[THDIM];
  int tid = threadIdx.x;
  if (tid < EHDIM) h[tid] = 0.f;
  float c = 0.f;
  __syncthreads();
  for (int t = 0; t < TDIM; t++) {
    if (tid < THDIM) {
      float acc = G[t * THDIM + tid];
      const unsigned* wp = WT + tid;
      const float4* h4 = (const float4*)h;
      for (int q = 0; q < 50; q++) {
        float4 hq = h4[q];
        unsigned wa = wp[(2 * q) * THDIM];
        unsigned wb = wp[(2 * q + 1) * THDIM];
        union { unsigned u; float f; } la, ha, lb, hb;
        la.u = wa << 16; ha.u = wa & 0xffff0000u;
        lb.u = wb << 16; hb.u = wb & 0xffff0000u;
        acc += la.f * hq.x + ha.f * hq.y + lb.f * hq.z + hb.f * hq.w;
      }
      g[tid] = acc;
    }
    __syncthreads();
    if (tid < EHDIM) {
      float si = 1.f / (1.f + __expf(-g[tid]));
      float sf = 1.f / (1.f + __expf(-g[200 + tid]));
      float sg = tanhf(g[400 + tid]);
      float so = 1.f / (1.f + __expf(-g[600 + tid]));
      c = sf * c + si * sg;
      float hn = so * tanhf(c);
      xout[t * EHDIM + tid] = hn;
      h[tid] = hn;
    }
    __syncthreads();
  }
}

// ---------------- eta chain (single block, W in LDS) ------------------------
#define WSTR 252
__global__ void k_eta(const float* __restrict__ Wmu, const float* __restrict__ bmu,
                      const float* __restrict__ Wls, const float* __restrict__ bls,
                      const float* __restrict__ lout, float* __restrict__ etas,
                      float* __restrict__ scal) {
  __shared__ __align__(16) float Wm[KDIM * WSTR + 4];
  __shared__ __align__(16) float Wl[KDIM * WSTR + 4];
  __shared__ __align__(16) float inp[256];
  __shared__ float mu_s[KDIM], ls_s[KDIM];
  int tid = threadIdx.x;  // 512
  for (int i = tid; i < KDIM * WSTR; i += 512) {
    int r = i / WSTR, c2 = i % WSTR;
    Wm[i] = (c2 < 250) ? Wmu[r * 250 + c2] : 0.f;
    Wl[i] = (c2 < 250) ? Wls[r * 250 + c2] : 0.f;
  }
  if (tid < 4) { Wm[KDIM * WSTR + tid] = 0.f; Wl[KDIM * WSTR + tid] = 0.f; }
  for (int i = tid; i < 256; i += 512) inp[i] = 0.f;
  __syncthreads();
  int wave = tid >> 6, lane = tid & 63;
  float kl = 0.f;
  for (int t = 0; t < TDIM; t++) {
    if (tid < EHDIM) inp[tid] = lout[t * EHDIM + tid];
    __syncthreads();
    float4 x4 = ((const float4*)inp)[lane];
    for (int jb = wave; jb < 2 * KDIM; jb += 8) {
      const float* Wrow = (jb < KDIM) ? (Wm + jb * WSTR) : (Wl + (jb - KDIM) * WSTR);
      float4 w4 = ((const float4*)Wrow)[lane];
      float acc = w4.x * x4.x + w4.y * x4.y + w4.z * x4.z + w4.w * x4.w;
      acc = wred64(acc);
      if (lane == 0) {
        if (jb < KDIM) mu_s[jb] = acc + bmu[jb];
        else ls_s[jb - KDIM] = acc + bls[jb - KDIM];
      }
    }
    __syncthreads();
    if (tid < 64) {
      float v = 0.f;
      if (tid < KDIM) {
        float m = mu_s[tid], ls = ls_s[tid];
        float ep = inp[EHDIM + tid];
        float d = m - ep;
        if (t == 0) v = 0.5f * ((__expf(ls) + d * d) / (1.f + EPSF) - 1.f - ls);
        else        v = 0.5f * ((__expf(ls) + d * d) / (DELTAF + EPSF) - 1.f + LOGD - ls);
        etas[t * KDIM + tid] = m;
      }
      v = wred64(v);
      if (tid == 0) kl += v;
    }
    __syncthreads();
    if (tid < KDIM) inp[EHDIM + tid] = mu_s[tid];
    __syncthreads();
  }
  if (tid == 0) scal[2] = kl;
}

// ---------------- h_pre = nb @ W_theta[:, :V]^T  (fp32 tiled, split-K) ------
// v2: 512 thr (8 waves), tile 128 TH x 128 B (100 valid), zc=67 x 14 k-tiles.
// grid (7,67)=469 blocks, launch_bounds(512,4) -> 2 blocks/CU = 4 waves/SIMD
// (was 329 blocks @ 1 wave/SIMD -> latency-bound, Occupancy 11.8%).
#define HP_BK 32
#define HP_STRIDE 132
__global__ __launch_bounds__(512, 4) void k_hpre(const float* __restrict__ nb,
                                                 const float* __restrict__ Wth,
                                                 float* __restrict__ h_pre) {
  __shared__ __align__(16) float As[HP_BK * HP_STRIDE];  // [k][b]
  __shared__ __align__(16) float Bs[HP_BK * HP_STRIDE];  // [k][th-local]
  int tid = threadIdx.x;
  int nt = blockIdx.x, zc = blockIdx.y;
  int kt0 = zc * 14, ktend = kt0 + 14;   // 67*14 = 938 k-tiles exactly
  float acc[4][8];
#pragma unroll
  for (int i = 0; i < 4; i++)
#pragma unroll
    for (int j = 0; j < 8; j++) acc[i][j] = 0.f;
  int tx = tid & 15, ty = tid >> 4;  // tx: 16 x 8 TH, ty: 32 x 4 B
  for (int kt = kt0; kt < ktend; kt++) {
    int v0 = kt * HP_BK;
#pragma unroll
    for (int r = 0; r < 2; r++) {
      int j = tid + r * 512;
      int row = j >> 3, c4 = (j & 7) * 4;
      int v = v0 + c4;
      float4 val = {0.f, 0.f, 0.f, 0.f};
      if (row < BDIM) {
        const float* base = nb + (size_t)row * VDIM + v;
        if (v + 3 < VDIM) val = *(const float4*)base;
        else {
          if (v < VDIM) val.x = base[0];
          if (v + 1 < VDIM) val.y = base[1];
          if (v + 2 < VDIM) val.z = base[2];
        }
      }
      As[(c4 + 0) * HP_STRIDE + row] = val.x;
      As[(c4 + 1) * HP_STRIDE + row] = val.y;
      As[(c4 + 2) * HP_STRIDE + row] = val.z;
      As[(c4 + 3) * HP_STRIDE + row] = val.w;
    }
#pragma unroll
    for (int r = 0; r < 2; r++) {
      int j = tid + r * 512;
      int row = j >> 3, c4 = (j & 7) * 4;
      int th = nt * 128 + row;
      int v = v0 + c4;
      float4 val = {0.f, 0.f, 0.f, 0.f};
      if (th < THDIM) {
        const float* base = Wth + (size_t)th * 30050 + v;
        if (v + 3 < VDIM) {
          float2 p0 = *(const float2*)base;
          float2 p1 = *(const float2*)(base + 2);
          val.x = p0.x; val.y = p0.y; val.z = p1.x; val.w = p1.y;
        } else {
          if (v < VDIM) val.x = base[0];
          if (v + 1 < VDIM) val.y = base[1];
          if (v + 2 < VDIM) val.z = base[2];
        }
      }
      Bs[(c4 + 0) * HP_STRIDE + row] = val.x;
      Bs[(c4 + 1) * HP_STRIDE + row] = val.y;
      Bs[(c4 + 2) * HP_STRIDE + row] = val.z;
      Bs[(c4 + 3) * HP_STRIDE + row] = val.w;
    }
    __syncthreads();
#pragma unroll
    for (int k = 0; k < HP_BK; k++) {
      float4 a0 = *(const float4*)&As[k * HP_STRIDE + ty * 4];
      float4 b0 = *(const float4*)&Bs[k * HP_STRIDE + tx * 8];
      float4 b1 = *(const float4*)&Bs[k * HP_STRIDE + tx * 8 + 4];
      float a[4] = {a0.x, a0.y, a0.z, a0.w};
      float b[8] = {b0.x, b0.y, b0.z, b0.w, b1.x, b1.y, b1.z, b1.w};
#pragma unroll
      for (int i = 0; i < 4; i++)
#pragma unroll
        for (int j = 0; j < 8; j++) acc[i][j] += a[i] * b[j];
    }
    __syncthreads();
  }
#pragma unroll
  for (int i = 0; i < 4; i++) {
    int bb = ty * 4 + i;
    if (bb >= BDIM) continue;
#pragma unroll
    for (int j = 0; j < 8; j++) {
      int th = nt * 128 + tx * 8 + j;
      if (th < THDIM) atomicAdd(&h_pre[bb * THDIM + th], acc[i][j]);
    }
  }
}

// ---------------- theta path: tanh, softmax, kl_theta -----------------------
__global__ void k_theta(const float* __restrict__ hpre, const float* __restrict__ bth,
                        const float* __restrict__ Wth, const float* __restrict__ Wmt,
                        const float* __restrict__ bmt, const float* __restrict__ Wlt,
                        const float* __restrict__ blt, const float* __restrict__ etas,
                        const int* __restrict__ times, float* __restrict__ theta,
                        float* __restrict__ scal) {
  __shared__ float et[KDIM];
  __shared__ float hl[THDIM];
  __shared__ float mu_s[KDIM], ls_s[KDIM];
  int b = blockIdx.x, tid = threadIdx.x;
  if (tid < KDIM) et[tid] = etas[times[b] * KDIM + tid];
  __syncthreads();
  for (int th = tid; th < THDIM; th += 256) {
    float acc = hpre[b * THDIM + th] + bth[th];
    const float* wrow = Wth + (size_t)th * 30050 + VDIM;
#pragma unroll 10
    for (int k = 0; k < KDIM; k++) acc += et[k] * wrow[k];
    hl[th] = tanhf(acc);
  }
  __syncthreads();
  int wave = tid >> 6, lane = tid & 63;
  for (int jb = wave; jb < 2 * KDIM; jb += 4) {
    const float* row = (jb < KDIM) ? (Wmt + jb * THDIM) : (Wlt + (jb - KDIM) * THDIM);
    float acc = 0.f;
#pragma unroll
    for (int m = 0; m < 13; m++) { int j = m * 64 + lane; if (j < THDIM) acc += row[j] * hl[j]; }
    acc = wred64(acc);
    if (lane == 0) {
      if (jb < KDIM) mu_s[jb] = acc + bmt[jb];
      else ls_s[jb - KDIM] = acc + blt[jb - KDIM];
    }
  }
  __syncthreads();
  if (tid < 64) {
    float m = (tid < KDIM) ? mu_s[tid] : -1e30f;
    float mx = m;
#pragma unroll
    for (int o = 32; o >= 1; o >>= 1) mx = fmaxf(mx, __shfl_xor(mx, o, 64));
    float e = (tid < KDIM) ? __expf(m - mx) : 0.f;
    float s = wred64(e);
    if (tid < KDIM) theta[b * KDIM + tid] = e / s;
    float v = 0.f;
    if (tid < KDIM) {
      float ls = ls_s[tid];
      float d = mu_s[tid] - et[tid];
      v = 0.5f * ((__expf(ls) + d * d) / (1.f + EPSF) - 1.f - ls);
    }
    v = wred64(v);
    if (tid == 0) atomicAdd(&scal[3], v);
  }
}

// ---------------- kl_alpha ---------------------------------------------------
__global__ void k_klalpha(const float* __restrict__ mu, const float* __restrict__ ls,
                          float* __restrict__ scal) {
  int idx = blockIdx.x * 256 + threadIdx.x;
  float v = 0.f;
  if (idx < KDIM * TDIM * EDIM) {
    int t = (idx / EDIM) % TDIM;
    float l = ls[idx], m = mu[idx];
    if (t == 0) v = 0.5f * ((__expf(l) + m * m) / (1.f + EPSF) - 1.f - l);
    else { float d = m - mu[idx - EDIM]; v = 0.5f * ((__expf(l) + d * d) / (DELTAF + EPSF) - 1.f + LOGD - l); }
  }
  v = wred64(v);
  __shared__ float p[4];
  if ((threadIdx.x & 63) == 0) p[threadIdx.x >> 6] = v;
  __syncthreads();
  if (threadIdx.x == 0) atomicAdd(&scal[1], p[0] + p[1] + p[2] + p[3]);
}

// ---------------- time buckets ----------------------------------------------
__global__ void k_bucket(const int* __restrict__ times, int* __restrict__ bcnt,
                         int* __restrict__ bucket) {
  __shared__ int cnt[TDIM];
  int tid = threadIdx.x;  // 128
  if (tid < TDIM) cnt[tid] = 0;
  __syncthreads();
  if (tid < BDIM) {
    int t = times[tid];
    int s = atomicAdd(&cnt[t], 1);
    bucket[t * 128 + s] = tid;
  }
  __syncthreads();
  if (tid < TDIM) bcnt[tid] = cnt[tid];
}

// ---------------- wgt[b][k] = theta[b][k] / Z[t_b*64+k] ---------------------
__global__ void k_wgt(const float* __restrict__ theta, const float* __restrict__ Z,
                      const int* __restrict__ times, float* __restrict__ wgt) {
  int idx = blockIdx.x * 256 + threadIdx.x;  // 6400
  if (idx >= BDIM * 64) return;
  int b = idx >> 6, k = idx & 63;
  float v = 0.f;
  if (k < KDIM) v = theta[b * KDIM + k] / Z[times[b] * 64 + k];
  wgt[idx] = v;
}

// ================= B-stationary MFMA GEMM (both passes) =====================
template <bool PASSB>
__global__ __launch_bounds__(512, 2) void k_gemm(
    const unsigned short* __restrict__ A2, const unsigned short* __restrict__ B2,
    float* __restrict__ Z, const float* __restrict__ wgt,
    const float* __restrict__ bows, const int* __restrict__ bcnt,
    const int* __restrict__ bucket, float* __restrict__ scal) {
  extern __shared__ __align__(16) unsigned short Bs[];  // [128][320] swizzled
  __shared__ float p[8];
  int tid = threadIdx.x, wv = tid >> 6, lane = tid & 63;
  int vbase = blockIdx.x * 128;
  int r15 = lane & 15, gh = lane >> 4, x7 = r15 & 7;

  // ---- stage 80 KB linearly: 80 chunks of 1 KB, 10 per wave
  const unsigned short* gB = B2 + (size_t)vbase * KPAD;
#pragma unroll
  for (int c = 0; c < 10; ++c) {
    int chunk = wv * 10 + c;
    gload_lds16(gB + chunk * 512 + lane * 8, Bs + chunk * 512);
  }
  __syncthreads();

  const unsigned short* Br = Bs + r15 * KPAD;
  float nacc = 0.f;

  for (int jj = 0; jj < 5; ++jj) {
    int q = jj * 8 + wv;  // t-quad owned by this wave this round
    f32x4 acc[4][8];
#pragma unroll
    for (int si = 0; si < 4; ++si)
#pragma unroll
      for (int sj = 0; sj < 8; ++sj) acc[si][sj] = (f32x4){0.f, 0.f, 0.f, 0.f};

    const bf16x8* ab = (const bf16x8*)(A2 + (size_t)(q * 64 + r15) * KPAD) + gh;
#pragma unroll 2
    for (int kk = 0; kk < 10; ++kk) {
      bf16x8 a0 = ab[kk * 4];
      bf16x8 a1 = ab[640 + kk * 4];
      bf16x8 a2 = ab[1280 + kk * 4];
      bf16x8 a3 = ab[1920 + kk * 4];
      int spo = (((kk * 4 + gh) ^ x7) << 3);
#pragma unroll
      for (int sj = 0; sj < 8; ++sj) {
        bf16x8 b = *(const bf16x8*)(Br + sj * 5120 + spo);
        acc[0][sj] = __builtin_amdgcn_mfma_f32_16x16x32_bf16(a0, b, acc[0][sj], 0, 0, 0);
        acc[1][sj] = __builtin_amdgcn_mfma_f32_16x16x32_bf16(a1, b, acc[1][sj], 0, 0, 0);
        acc[2][sj] = __builtin_amdgcn_mfma_f32_16x16x32_bf16(a2, b, acc[2][sj], 0, 0, 0);
        acc[3][sj] = __builtin_amdgcn_mfma_f32_16x16x32_bf16(a3, b, acc[3][sj], 0, 0, 0);
      }
    }

    if (!PASSB) {
      // Z[m] += sum_v exp(logit)
#pragma unroll
      for (int si = 0; si < 4; ++si) {
#pragma unroll
        for (int r = 0; r < 4; ++r) {
          float es = 0.f;
#pragma unroll
          for (int sj = 0; sj < 8; ++sj) {
            int v = vbase + sj * 16 + r15;
            es += (v < VDIM) ? __expf(acc[si][sj][r]) : 0.f;
          }
          es += __shfl_xor(es, 1, 64); es += __shfl_xor(es, 2, 64);
          es += __shfl_xor(es, 4, 64); es += __shfl_xor(es, 8, 64);
          if (r15 == 0) atomicAdd(&Z[q * 64 + si * 16 + gh * 4 + r], es);
        }
      }
    } else {
#pragma unroll
      for (int si = 0; si < 4; ++si)
#pragma unroll
        for (int sj = 0; sj < 8; ++sj)
#pragma unroll
          for (int r = 0; r < 4; ++r) acc[si][sj][r] = __expf(acc[si][sj][r]);
      int cnt = bcnt[q];
      for (int n = 0; n < cnt; ++n) {
        int b = bucket[q * 128 + n];
        float4 w4[4];
#pragma unroll
        for (int si = 0; si < 4; ++si)
          w4[si] = *(const float4*)(wgt + b * 64 + si * 16 + gh * 4);
#pragma unroll
        for (int sj = 0; sj < 8; ++sj) {
          float local = 0.f;
#pragma unroll
          for (int si = 0; si < 4; ++si)
            local += w4[si].x * acc[si][sj][0] + w4[si].y * acc[si][sj][1] +
                     w4[si].z * acc[si][sj][2] + w4[si].w * acc[si][sj][3];
          local += __shfl_xor(local, 16, 64);
          local += __shfl_xor(local, 32, 64);
          int v = vbase + sj * 16 + r15;
          if (lane < 16 && v < VDIM)
            nacc += bows[(size_t)b * VDIM + v] * __logf(local + EPSF);
        }
      }
    }
  }

  if (PASSB) {
    nacc = wred64(nacc);
    if (lane == 0) p[wv] = nacc;
    __syncthreads();
    if (tid == 0)
      atomicAdd(&scal[0], p[0] + p[1] + p[2] + p[3] + p[4] + p[5] + p[6] + p[7]);
  }
}

// ================= fallback-path MFMA kernels (round-1, known-good) =========
__device__ inline void stage_B(const float* __restrict__ we, int vbase,
                               unsigned short* LB, int tid) {
  for (int q = tid; q < VT * 75; q += 256) {
    int vp = q / 75, e4 = (q % 75) * 4;
    float4 w = *(const float4*)(we + (size_t)(vbase + vp) * EDIM + e4);
    unsigned* p32 = (unsigned*)(LB + vp * LBSTR + e4);
    p32[0] = (unsigned)f2bf(w.x) | ((unsigned)f2bf(w.y) << 16);
    p32[1] = (unsigned)f2bf(w.z) | ((unsigned)f2bf(w.w) << 16);
  }
  for (int q = tid; q < VT * 28; q += 256) {
    int vp = q / 28, e = 300 + q % 28;
    LB[vp * LBSTR + e] = 0;
  }
}

__device__ inline void quad_mainloop(const unsigned short* __restrict__ A2,
                                     const unsigned short* LB, int quad, int lane,
                                     f32x4 (&acc)[4][5]) {
  int mrow = quad * 64 + (lane & 15);
  int eoff = (lane >> 4) * 8;
  const bf16x8* ap[4];
#pragma unroll
  for (int ss = 0; ss < 4; ss++)
    ap[ss] = (const bf16x8*)(A2 + (size_t)(mrow + ss * 16) * KPAD + eoff);
  const unsigned short* bp = LB + (lane & 15) * LBSTR + eoff;
#pragma unroll
  for (int kk = 0; kk < 10; kk++) {
    bf16x8 a[4];
#pragma unroll
    for (int ss = 0; ss < 4; ss++) a[ss] = ap[ss][kk * 4];
#pragma unroll
    for (int cf = 0; cf < 5; cf++) {
      bf16x8 b = *(const bf16x8*)(bp + cf * 16 * LBSTR + kk * 32);
#pragma unroll
      for (int ss = 0; ss < 4; ss++)
        acc[ss][cf] = __builtin_amdgcn_mfma_f32_16x16x32_bf16(a[ss], b, acc[ss][cf], 0, 0, 0);
    }
  }
}

__global__ __launch_bounds__(256, 2) void k_passA(const float* __restrict__ we,
                                                  const unsigned short* __restrict__ A2,
                                                  float* __restrict__ Z) {
  __shared__ __align__(16) unsigned short LB[VT * LBSTR];
  int tid = threadIdx.x, vbase = blockIdx.x * VT;
  stage_B(we, vbase, LB, tid);
  __syncthreads();
  int wave = tid >> 6, lane = tid & 63;
  for (int q = wave; q < TDIM; q += 4) {
    f32x4 acc[4][5];
#pragma unroll
    for (int ss = 0; ss < 4; ss++)
#pragma unroll
      for (int cf = 0; cf < 5; cf++) acc[ss][cf] = (f32x4){0.f, 0.f, 0.f, 0.f};
    quad_mainloop(A2, LB, q, lane, acc);
#pragma unroll
    for (int ss = 0; ss < 4; ss++) {
#pragma unroll
      for (int r = 0; r < 4; r++) {
        float s = __expf(acc[ss][0][r]) + __expf(acc[ss][1][r]) + __expf(acc[ss][2][r]) +
                  __expf(acc[ss][3][r]) + __expf(acc[ss][4][r]);
        s += __shfl_xor(s, 1, 64); s += __shfl_xor(s, 2, 64);
        s += __shfl_xor(s, 4, 64); s += __shfl_xor(s, 8, 64);
        if ((lane & 15) == 0)
          atomicAdd(&Z[q * 64 + ss * 16 + (lane >> 4) * 4 + r], s);
      }
    }
  }
}

__global__ __launch_bounds__(256, 2) void k_passB(const float* __restrict__ we,
                                                  const unsigned short* __restrict__ A2,
                                                  const float* __restrict__ wgt,
                                                  const float* __restrict__ bows,
                                                  const int* __restrict__ bcnt,
                                                  const int* __restrict__ bucket,
                                                  float* __restrict__ scal) {
  __shared__ __align__(16) unsigned short LB[VT * LBSTR];
  int tid = threadIdx.x, vbase = blockIdx.x * VT;
  stage_B(we, vbase, LB, tid);
  __syncthreads();
  int wave = tid >> 6, lane = tid & 63;
  float nacc = 0.f;
  for (int t = wave; t < TDIM; t += 4) {
    f32x4 acc[4][5];
#pragma unroll
    for (int ss = 0; ss < 4; ss++)
#pragma unroll
      for (int cf = 0; cf < 5; cf++) acc[ss][cf] = (f32x4){0.f, 0.f, 0.f, 0.f};
    quad_mainloop(A2, LB, t, lane, acc);
#pragma unroll
    for (int ss = 0; ss < 4; ss++)
#pragma unroll
      for (int cf = 0; cf < 5; cf++)
#pragma unroll
        for (int r = 0; r < 4; r++) acc[ss][cf][r] = __expf(acc[ss][cf][r]);
    int cnt = bcnt[t];
    for (int n = 0; n < cnt; n++) {
      int b = bucket[t * 128 + n];
      float4 w[4];
#pragma unroll
      for (int ss = 0; ss < 4; ss++)
        w[ss] = *(const float4*)(wgt + b * 64 + ss * 16 + (lane >> 4) * 4);
#pragma unroll
      for (int cf = 0; cf < 5; cf++) {
        float local = 0.f;
#pragma unroll
        for (int ss = 0; ss < 4; ss++)
          local += w[ss].x * acc[ss][cf][0] + w[ss].y * acc[ss][cf][1] +
                   w[ss].z * acc[ss][cf][2] + w[ss].w * acc[ss][cf][3];
        local += __shfl_xor(local, 16, 64);
        local += __shfl_xor(local, 32, 64);
        int v = vbase + cf * 16 + (lane & 15);
        float contrib = bows[(size_t)b * VDIM + v] * __logf(local + EPSF);
        if (lane < 16) nacc += contrib;
      }
    }
  }
  nacc = wred64(nacc);
  __shared__ float p[4];
  if (lane == 0) p[wave] = nacc;
  __syncthreads();
  if (tid == 0) atomicAdd(&scal[0], p[0] + p[1] + p[2] + p[3]);
}

// ---------------- finalize ---------------------------------------------------
__global__ void k_finalize(const float* __restrict__ scal, float* __restrict__ out) {
  if (threadIdx.x == 0 && blockIdx.x == 0) {
    float nll = -scal[0];
    out[0] = nll + scal[1] + scal[2] + scal[3];
    out[1] = nll;
    out[2] = scal[1];
    out[3] = scal[2];
    out[4] = scal[3];
  }
}

extern "C" void kernel_launch(void* const* d_in, const int* in_sizes, int n_in,
                              void* d_out, int out_size, void* d_ws, size_t ws_size,
                              hipStream_t stream) {
  const float* bows  = (const float*)d_in[0];
  const float* nbows = (const float*)d_in[1];
  const float* rnn   = (const float*)d_in[2];
  const float* wemb  = (const float*)d_in[3];
  const float* mua   = (const float*)d_in[4];
  const float* lsa   = (const float*)d_in[5];
  const float* Wth   = (const float*)d_in[6];
  const float* bth   = (const float*)d_in[7];
  const float* Wmt   = (const float*)d_in[8];
  const float* bmt   = (const float*)d_in[9];
  const float* Wlt   = (const float*)d_in[10];
  const float* blt   = (const float*)d_in[11];
  const float* Wmap  = (const float*)d_in[12];
  const float* bmap  = (const float*)d_in[13];
  const float* Wih   = (const float*)d_in[14];
  const float* Whh   = (const float*)d_in[15];
  const float* bihp  = (const float*)d_in[16];
  const float* bhhp  = (const float*)d_in[17];
  const float* Wme   = (const float*)d_in[18];
  const float* bme   = (const float*)d_in[19];
  const float* Wle   = (const float*)d_in[20];
  const float* ble   = (const float*)d_in[21];
  const int* times   = (const int*)d_in[22];

  float* ws = (float*)d_ws;
  float* scal  = ws;                 // 8
  float* Z     = ws + 8;             // 2560
  float* hpre  = ws + 2568;          // 80000
  float* omap  = ws + 82568;         // 8000   (end of zeroed region: 90568 floats)
  float* xa    = ws + 90568;         // 8000
  float* xb    = ws + 98568;         // 8000
  float* lout  = ws + 106568;        // 8000
  float* Gin   = ws + 114568;        // 32000
  unsigned* WhhT = (unsigned*)(ws + 146568);   // 240000
  float* etas  = ws + 386568;        // 2000
  float* theta = ws + 388568;        // 5000
  float* wgt   = ws + 393568;        // 6400
  int* bcnt    = (int*)(ws + 399968);          // 64
  int* bucket  = (int*)(ws + 400032);          // 5120
  unsigned short* A2 = (unsigned short*)(ws + 405152);  // 819200 ushorts -> ends 814752
  unsigned short* B2 = (unsigned short*)(ws + 814752);  // 30080*320 ushorts = 19.25 MB

  // fast path needs ws up to byte offset 814752*4 + 19251200 = 22510208
  bool fast = ws_size >= 23000000u;

  if (fast) {
    static bool attr_set = false;
    if (!attr_set) {
      auto kA = k_gemm<false>;
      auto kB = k_gemm<true>;
      (void)hipFuncSetAttribute((const void*)kA,
                                hipFuncAttributeMaxDynamicSharedMemorySize, GEMM_LDS);
      (void)hipFuncSetAttribute((const void*)kB,
                                hipFuncAttributeMaxDynamicSharedMemorySize, GEMM_LDS);
      attr_set = true;
    }
  }

  hipMemsetAsync(ws, 0, 90568 * sizeof(float), stream);

  k_prep_A2<<<3200, 256, 0, stream>>>(mua, A2);
  if (fast) k_prep_B<<<9400, 256, 0, stream>>>(wemb, B2);
  k_map2<<<dim3(313, 2), 256, 0, stream>>>(rnn, Wmap, bmap, omap);
  k_wt<<<300, 256, 0, stream>>>(Whh, WhhT);
  k_bucket<<<1, 128, 0, stream>>>(times, bcnt, bucket);

  if (fast)
    k_gemm<false><<<235, 512, GEMM_LDS, stream>>>(A2, B2, Z, nullptr, nullptr,
                                                  nullptr, nullptr, nullptr);
  else
    k_passA<<<NBLK_V, 256, 0, stream>>>(wemb, A2, Z);

  k_igemm<<<400, 256, 0, stream>>>(Wih, bihp, bhhp, omap, Gin, 0);
  k_rec<<<1, 1024, 0, stream>>>(WhhT, Gin, xa);
  k_igemm<<<400, 256, 0, stream>>>(Wih, bihp, bhhp, xa, Gin, 1);
  k_rec<<<1, 1024, 0, stream>>>(WhhT + 100 * 800, Gin, xb);
  k_igemm<<<400, 256, 0, stream>>>(Wih, bihp, bhhp, xb, Gin, 2);
  k_rec<<<1, 1024, 0, stream>>>(WhhT + 200 * 800, Gin, lout);

  k_eta<<<1, 512, 0, stream>>>(Wme, bme, Wle, ble, lout, etas, scal);
  k_hpre<<<dim3(7, 67), 512, 0, stream>>>(nbows, Wth, hpre);
  k_theta<<<100, 256, 0, stream>>>(hpre, bth, Wth, Wmt, bmt, Wlt, blt, etas, times, theta, scal);
  k_wgt<<<25, 256, 0, stream>>>(theta, Z, times, wgt);
  k_klalpha<<<2344, 256, 0, stream>>>(mua, lsa, scal);

  if (fast)
    k_gemm<true><<<235, 512, GEMM_LDS, stream>>>(A2, B2, Z, wgt, bows, bcnt,
                                                 bucket, scal);
  else
    k_passB<<<NBLK_V, 256, 0, stream>>>(wemb, A2, wgt, bows, bcnt, bucket, scal);

  k_finalize<<<1, 64, 0, stream>>>(scal, (float*)d_out);
}

// Round 4
// 1729.108 us; speedup vs baseline: 1.2121x; 1.0632x over previous
//
#include <hip/hip_runtime.h>

#define KDIM 50
#define TDIM 40
#define VDIM 30000
#define THDIM 800
#define EHDIM 200
#define EDIM 300
#define BDIM 100
#define DELTAF 0.005f
#define EPSF 1e-6f
#define LOGD (-5.2983174f)
#define MROWS 2560   // TDIM*64 rows for MFMA A operand
#define KPAD 320     // E padded to 320
#define VROWS 30080  // V padded to 235*128
#define VT 80        // v-tile per MFMA block (fallback path)
#define NBLK_V 375   // 30000/80 (fallback path)
#define LBSTR 328    // fallback LDS B-tile row stride
#define GEMM_LDS 81920  // 128 rows * 320 cols * 2B

typedef __attribute__((ext_vector_type(8))) short bf16x8;
typedef __attribute__((ext_vector_type(4))) float f32x4;
typedef unsigned int u32;

__device__ inline float wred64(float v) {
  v += __shfl_xor(v, 32, 64); v += __shfl_xor(v, 16, 64);
  v += __shfl_xor(v, 8, 64);  v += __shfl_xor(v, 4, 64);
  v += __shfl_xor(v, 2, 64);  v += __shfl_xor(v, 1, 64);
  return v;
}

__device__ inline unsigned short f2bf(float f) {
  union { float f; unsigned u; } x; x.f = f;
  unsigned r = x.u + 0x7fffu + ((x.u >> 16) & 1u);
  return (unsigned short)(r >> 16);
}

__device__ inline void gload_lds16(const void* g, void* l) {
  __builtin_amdgcn_global_load_lds(
      (const __attribute__((address_space(1))) u32*)g,
      (__attribute__((address_space(3))) u32*)l, 16, 0, 0);
}

// ---------------- A2 prep: mu_q_alpha[k][t][e] -> bf16 A2[t*64+k][e<320] ----
__global__ void k_prep_A2(const float* __restrict__ mu_q, unsigned short* __restrict__ A2) {
  int idx = blockIdx.x * 256 + threadIdx.x;   // 2560*320 = 819200
  if (idx >= MROWS * KPAD) return;
  int m = idx / KPAD, e = idx % KPAD;
  int t = m >> 6, kp = m & 63;
  float v = 0.f;
  if (kp < KDIM && e < EDIM) v = mu_q[(kp * TDIM + t) * EDIM + e];
  A2[idx] = f2bf(v);
}

// ---------------- B2 prep: word_emb fp32 [30000][300] -> bf16 [30080][320] --
// PRE-SWIZZLED: 16B slot s (e>>3) stored at physical slot s ^ (v&7), so the
// GEMM's linear global_load_lds staging + XOR'd ds_read_b128 is bank-balanced.
__global__ void k_prep_B(const float* __restrict__ we, unsigned short* __restrict__ B2) {
  int idx = blockIdx.x * 256 + threadIdx.x;   // 30080*80 = 2406400
  if (idx >= VROWS * 80) return;
  int v = idx / 80, e4 = (idx % 80) * 4;
  ushort4 o = {0, 0, 0, 0};
  if (v < VDIM && e4 < EDIM) {
    float4 w = *(const float4*)(we + (size_t)v * EDIM + e4);
    o.x = f2bf(w.x); o.y = f2bf(w.y); o.z = f2bf(w.z); o.w = f2bf(w.w);
  }
  int dcol = (((e4 >> 3) ^ (v & 7)) << 3) | (e4 & 7);
  *(ushort4*)(B2 + (size_t)v * KPAD + dcol) = o;
}

// ---------------- out_map = rnn_inp @ W_map^T + b_map  [40,200] -------------
#define MP_VS 96
#define RS_STR 44
#define WS_STR 104
__global__ __launch_bounds__(256) void k_map2(const float* __restrict__ rnn,
                                              const float* __restrict__ Wmap,
                                              const float* __restrict__ bmap,
                                              float* __restrict__ omap) {
  __shared__ __align__(16) float rs[MP_VS * RS_STR];
  __shared__ __align__(16) float wsb[MP_VS * WS_STR];
  int c = blockIdx.x, eh = blockIdx.y;
  int v0 = c * MP_VS, e0 = eh * 100;
  int tid = threadIdx.x;
  for (int idx = tid; idx < TDIM * MP_VS; idx += 256) {
    int t = idx / MP_VS, vv = idx % MP_VS;
    int v = v0 + vv;
    rs[vv * RS_STR + t] = (v < VDIM) ? rnn[(size_t)t * VDIM + v] : 0.f;
  }
  for (int idx = tid; idx < 100 * MP_VS; idx += 256) {
    int e = idx / MP_VS, vv = idx % MP_VS;
    int v = v0 + vv;
    wsb[vv * WS_STR + e] = (v < VDIM) ? Wmap[(size_t)(e0 + e) * VDIM + v] : 0.f;
  }
  __syncthreads();
  if (tid >= 250) return;
  int eg = tid / 10, tg = tid % 10;
  float acc[4][4];
#pragma unroll
  for (int i = 0; i < 4; i++)
#pragma unroll
    for (int j = 0; j < 4; j++) acc[i][j] = 0.f;
  int nvv = min(MP_VS, VDIM - v0);
  for (int vv = 0; vv < nvv; vv++) {
    float4 wv = *(const float4*)&wsb[vv * WS_STR + eg * 4];
    float4 rv = *(const float4*)&rs[vv * RS_STR + tg * 4];
    float wa[4] = {wv.x, wv.y, wv.z, wv.w};
    float ra[4] = {rv.x, rv.y, rv.z, rv.w};
#pragma unroll
    for (int i = 0; i < 4; i++)
#pragma unroll
      for (int j = 0; j < 4; j++) acc[i][j] += wa[i] * ra[j];
  }
#pragma unroll
  for (int i = 0; i < 4; i++) {
    int e = e0 + eg * 4 + i;
#pragma unroll
    for (int j = 0; j < 4; j++) {
      int t = tg * 4 + j;
      float a = acc[i][j];
      if (c == 0) a += bmap[e];
      atomicAdd(&omap[t * EHDIM + e], a);
    }
  }
}

// ---------------- Whh transpose+pack to bf16 pairs: WhhT[l][jp][i] ----------
__global__ void k_wt(const float* __restrict__ Whh, unsigned* __restrict__ WhhT) {
  int l = blockIdx.x / 100, jp = blockIdx.x % 100;
  for (int i = threadIdx.x; i < THDIM; i += 256) {
    float w0 = Whh[(l * THDIM + i) * EHDIM + 2 * jp];
    float w1 = Whh[(l * THDIM + i) * EHDIM + 2 * jp + 1];
    WhhT[(l * 100 + jp) * THDIM + i] = (unsigned)f2bf(w0) | ((unsigned)f2bf(w1) << 16);
  }
}

// ---------------- LSTM input GEMM: G[t][i] = Wih[l][i]·x[t] + bih + bhh -----
__global__ void k_igemm(const float* __restrict__ Wih, const float* __restrict__ bih,
                        const float* __restrict__ bhh, const float* __restrict__ x,
                        float* __restrict__ G, int l) {
  int wave = threadIdx.x >> 6, lane = threadIdx.x & 63;
  int d0 = blockIdx.x * 80 + wave * 20;
  for (int n = 0; n < 20; n++) {
    int d = d0 + n;
    int t = d / THDIM, i = d % THDIM;
    const float* row = Wih + (l * THDIM + i) * EHDIM;
    const float* xt = x + t * EHDIM;
    float acc = 0.f;
#pragma unroll
    for (int m = 0; m < 4; m++) { int j = m * 64 + lane; if (j < EHDIM) acc += row[j] * xt[j]; }
    acc = wred64(acc);
    if (lane == 0) G[t * THDIM + i] = acc + bih[l * THDIM + i] + bhh[l * THDIM + i];
  }
}

// ---------------- LSTM recurrence (single block, streams bf16 WhhT) ---------
__global__ __launch_bounds__(1024) void k_rec(const unsigned* __restrict__ WT,
                                              const float* __restrict__ G,
                                              float* __restrict__ xout) {
  __shared__ __align__(16) float h[EHDIM];
  __shared__ float g[THDIM];
  int tid = threadIdx.x;
  if (tid < EHDIM) h[tid] = 0.f;
  float c = 0.f;
  __syncthreads();
  for (int t = 0; t < TDIM; t++) {
    if (tid < THDIM) {
      float acc = G[t * THDIM + tid];
      const unsigned* wp = WT + tid;
      const float4* h4 = (const float4*)h;
      for (int q = 0; q < 50; q++) {
        float4 hq = h4[q];
        unsigned wa = wp[(2 * q) * THDIM];
        unsigned wb = wp[(2 * q + 1) * THDIM];
        union { unsigned u; float f; } la, ha, lb, hb;
        la.u = wa << 16; ha.u = wa & 0xffff0000u;
        lb.u = wb << 16; hb.u = wb & 0xffff0000u;
        acc += la.f * hq.x + ha.f * hq.y + lb.f * hq.z + hb.f * hq.w;
      }
      g[tid] = acc;
    }
    __syncthreads();
    if (tid < EHDIM) {
      float si = 1.f / (1.f + __expf(-g[tid]));
      float sf = 1.f / (1.f + __expf(-g[200 + tid]));
      float sg = tanhf(g[400 + tid]);
      float so = 1.f / (1.f + __expf(-g[600 + tid]));
      c = sf * c + si * sg;
      float hn = so * tanhf(c);
      xout[t * EHDIM + tid] = hn;
      h[tid] = hn;
    }
    __syncthreads();
  }
}

// ---------------- eta chain (single block, W in LDS) ------------------------
#define WSTR 252
__global__ void k_eta(const float* __restrict__ Wmu, const float* __restrict__ bmu,
                      const float* __restrict__ Wls, const float* __restrict__ bls,
                      const float* __restrict__ lout, float* __restrict__ etas,
                      float* __restrict__ scal) {
  __shared__ __align__(16) float Wm[KDIM * WSTR + 4];
  __shared__ __align__(16) float Wl[KDIM * WSTR + 4];
  __shared__ __align__(16) float inp[256];
  __shared__ float mu_s[KDIM], ls_s[KDIM];
  int tid = threadIdx.x;  // 512
  for (int i = tid; i < KDIM * WSTR; i += 512) {
    int r = i / WSTR, c2 = i % WSTR;
    Wm[i] = (c2 < 250) ? Wmu[r * 250 + c2] : 0.f;
    Wl[i] = (c2 < 250) ? Wls[r * 250 + c2] : 0.f;
  }
  if (tid < 4) { Wm[KDIM * WSTR + tid] = 0.f; Wl[KDIM * WSTR + tid] = 0.f; }
  for (int i = tid; i < 256; i += 512) inp[i] = 0.f;
  __syncthreads();
  int wave = tid >> 6, lane = tid & 63;
  float kl = 0.f;
  for (int t = 0; t < TDIM; t++) {
    if (tid < EHDIM) inp[tid] = lout[t * EHDIM + tid];
    __syncthreads();
    float4 x4 = ((const float4*)inp)[lane];
    for (int jb = wave; jb < 2 * KDIM; jb += 8) {
      const float* Wrow = (jb < KDIM) ? (Wm + jb * WSTR) : (Wl + (jb - KDIM) * WSTR);
      float4 w4 = ((const float4*)Wrow)[lane];
      float acc = w4.x * x4.x + w4.y * x4.y + w4.z * x4.z + w4.w * x4.w;
      acc = wred64(acc);
      if (lane == 0) {
        if (jb < KDIM) mu_s[jb] = acc + bmu[jb];
        else ls_s[jb - KDIM] = acc + bls[jb - KDIM];
      }
    }
    __syncthreads();
    if (tid < 64) {
      float v = 0.f;
      if (tid < KDIM) {
        float m = mu_s[tid], ls = ls_s[tid];
        float ep = inp[EHDIM + tid];
        float d = m - ep;
        if (t == 0) v = 0.5f * ((__expf(ls) + d * d) / (1.f + EPSF) - 1.f - ls);
        else        v = 0.5f * ((__expf(ls) + d * d) / (DELTAF + EPSF) - 1.f + LOGD - ls);
        etas[t * KDIM + tid] = m;
      }
      v = wred64(v);
      if (tid == 0) kl += v;
    }
    __syncthreads();
    if (tid < KDIM) inp[EHDIM + tid] = mu_s[tid];
    __syncthreads();
  }
  if (tid == 0) scal[2] = kl;
}

// ---------------- h_pre = nb @ W_theta[:, :V]^T  (MFMA, bf16 hi+lo split) ---
// v3: matrix cores. C[th][b]: A = Wth rows (M=800, 13x64 tiles), B = nb rows
// (N=100 pad 112 = 7x16). Split-K: 47 chunks x 20 K-steps (BK=32), grid 611.
// fp32 staged via regs -> hi/lo bf16 pair -> LDS; 3 MFMA per (si,sj) tile
// (hi*hi + hi*lo + lo*hi) gives ~2^-17 per-element accuracy, fp32 accum.
// LDS row stride 40 bf16 (80 B): b128 frag reads spread uniformly over all 8
// bank-quads (vs 4-way conflict of the old fp32 SIMT version).
#define HPM_STR 40
__global__ __launch_bounds__(256, 2) void k_hpre(const float* __restrict__ nb,
                                                 const float* __restrict__ Wth,
                                                 float* __restrict__ h_pre) {
  __shared__ __align__(16) unsigned short Ahi[64 * HPM_STR];
  __shared__ __align__(16) unsigned short Alo[64 * HPM_STR];
  __shared__ __align__(16) unsigned short Bhi[112 * HPM_STR];
  __shared__ __align__(16) unsigned short Blo[112 * HPM_STR];
  int tid = threadIdx.x, wv = tid >> 6, lane = tid & 63;
  int r15 = lane & 15, gh = lane >> 4;
  int mt = blockIdx.x;                        // 13 m-tiles of 64 TH rows
  int s0 = blockIdx.y * 20;
  int s1 = min(s0 + 20, 938);                 // 938 K-steps of 32 cover 30016
  f32x4 acc[7];
#pragma unroll
  for (int j = 0; j < 7; ++j) acc[j] = (f32x4){0.f, 0.f, 0.f, 0.f};
  int srow = tid >> 3, sk4 = (tid & 7) * 4;   // float col within 32-k tile
  for (int s = s0; s < s1; ++s) {
    int k = s * 32 + sk4;
    bool kok = (k + 3) < VDIM;                // 30000%4==0: never straddles
    // ---- global -> regs (latency overlaps prev iteration's MFMA)
    float4 av[2], bv[4];
#pragma unroll
    for (int it = 0; it < 2; ++it) {
      int th = mt * 64 + srow + it * 32;
      float4 v = {0.f, 0.f, 0.f, 0.f};
      if (th < THDIM && kok) {
        const float* p = Wth + (size_t)th * 30050 + k;  // 8B-aligned only
        float2 p0 = *(const float2*)p;
        float2 p1 = *(const float2*)(p + 2);
        v.x = p0.x; v.y = p0.y; v.z = p1.x; v.w = p1.y;
      }
      av[it] = v;
    }
#pragma unroll
    for (int it = 0; it < 4; ++it) {
      int b = srow + it * 32;
      float4 v = {0.f, 0.f, 0.f, 0.f};
      if (b < BDIM && kok) v = *(const float4*)(nb + (size_t)b * VDIM + k);
      bv[it] = v;
    }
    __syncthreads();   // all waves done reading LDS from previous step
    // ---- convert fp32 -> (hi, lo) bf16 and write LDS
#pragma unroll
    for (int it = 0; it < 2; ++it) {
      int row = srow + it * 32;
      float fa[4] = {av[it].x, av[it].y, av[it].z, av[it].w};
      unsigned short hh[4], ll[4];
#pragma unroll
      for (int u = 0; u < 4; ++u) {
        unsigned short hv = f2bf(fa[u]);
        union { unsigned uu; float f; } uf; uf.uu = (unsigned)hv << 16;
        hh[u] = hv; ll[u] = f2bf(fa[u] - uf.f);
      }
      *(ushort4*)(Ahi + row * HPM_STR + sk4) = (ushort4){hh[0], hh[1], hh[2], hh[3]};
      *(ushort4*)(Alo + row * HPM_STR + sk4) = (ushort4){ll[0], ll[1], ll[2], ll[3]};
    }
#pragma unroll
    for (int it = 0; it < 4; ++it) {
      int row = srow + it * 32;
      if (row < 112) {
        float fb[4] = {bv[it].x, bv[it].y, bv[it].z, bv[it].w};
        unsigned short hh[4], ll[4];
#pragma unroll
        for (int u = 0; u < 4; ++u) {
          unsigned short hv = f2bf(fb[u]);
          union { unsigned uu; float f; } uf; uf.uu = (unsigned)hv << 16;
          hh[u] = hv; ll[u] = f2bf(fb[u] - uf.f);
        }
        *(ushort4*)(Bhi + row * HPM_STR + sk4) = (ushort4){hh[0], hh[1], hh[2], hh[3]};
        *(ushort4*)(Blo + row * HPM_STR + sk4) = (ushort4){ll[0], ll[1], ll[2], ll[3]};
      }
    }
    __syncthreads();
    // ---- fragment reads + MFMA (wave wv owns A rows wv*16..+15)
    bf16x8 ah = *(const bf16x8*)(Ahi + (wv * 16 + r15) * HPM_STR + gh * 8);
    bf16x8 al = *(const bf16x8*)(Alo + (wv * 16 + r15) * HPM_STR + gh * 8);
#pragma unroll
    for (int sj = 0; sj < 7; ++sj) {
      bf16x8 bh = *(const bf16x8*)(Bhi + (sj * 16 + r15) * HPM_STR + gh * 8);
      bf16x8 bl = *(const bf16x8*)(Blo + (sj * 16 + r15) * HPM_STR + gh * 8);
      acc[sj] = __builtin_amdgcn_mfma_f32_16x16x32_bf16(ah, bh, acc[sj], 0, 0, 0);
      acc[sj] = __builtin_amdgcn_mfma_f32_16x16x32_bf16(ah, bl, acc[sj], 0, 0, 0);
      acc[sj] = __builtin_amdgcn_mfma_f32_16x16x32_bf16(al, bh, acc[sj], 0, 0, 0);
    }
  }
  // ---- epilogue: C row = th (lane>>4)*4+reg, col = b (lane&15)
#pragma unroll
  for (int sj = 0; sj < 7; ++sj) {
    int b = sj * 16 + r15;
    if (b >= BDIM) continue;
#pragma unroll
    for (int r = 0; r < 4; ++r) {
      int th = mt * 64 + wv * 16 + gh * 4 + r;
      if (th < THDIM) atomicAdd(&h_pre[b * THDIM + th], acc[sj][r]);
    }
  }
}

// ---------------- theta path: tanh, softmax, kl_theta -----------------------
__global__ void k_theta(const float* __restrict__ hpre, const float* __restrict__ bth,
                        const float* __restrict__ Wth, const float* __restrict__ Wmt,
                        const float* __restrict__ bmt, const float* __restrict__ Wlt,
                        const float* __restrict__ blt, const float* __restrict__ etas,
                        const int* __restrict__ times, float* __restrict__ theta,
                        float* __restrict__ scal) {
  __shared__ float et[KDIM];
  __shared__ float hl[THDIM];
  __shared__ float mu_s[KDIM], ls_s[KDIM];
  int b = blockIdx.x, tid = threadIdx.x;
  if (tid < KDIM) et[tid] = etas[times[b] * KDIM + tid];
  __syncthreads();
  for (int th = tid; th < THDIM; th += 256) {
    float acc = hpre[b * THDIM + th] + bth[th];
    const float* wrow = Wth + (size_t)th * 30050 + VDIM;
#pragma unroll 10
    for (int k = 0; k < KDIM; k++) acc += et[k] * wrow[k];
    hl[th] = tanhf(acc);
  }
  __syncthreads();
  int wave = tid >> 6, lane = tid & 63;
  for (int jb = wave; jb < 2 * KDIM; jb += 4) {
    const float* row = (jb < KDIM) ? (Wmt + jb * THDIM) : (Wlt + (jb - KDIM) * THDIM);
    float acc = 0.f;
#pragma unroll
    for (int m = 0; m < 13; m++) { int j = m * 64 + lane; if (j < THDIM) acc += row[j] * hl[j]; }
    acc = wred64(acc);
    if (lane == 0) {
      if (jb < KDIM) mu_s[jb] = acc + bmt[jb];
      else ls_s[jb - KDIM] = acc + blt[jb - KDIM];
    }
  }
  __syncthreads();
  if (tid < 64) {
    float m = (tid < KDIM) ? mu_s[tid] : -1e30f;
    float mx = m;
#pragma unroll
    for (int o = 32; o >= 1; o >>= 1) mx = fmaxf(mx, __shfl_xor(mx, o, 64));
    float e = (tid < KDIM) ? __expf(m - mx) : 0.f;
    float s = wred64(e);
    if (tid < KDIM) theta[b * KDIM + tid] = e / s;
    float v = 0.f;
    if (tid < KDIM) {
      float ls = ls_s[tid];
      float d = mu_s[tid] - et[tid];
      v = 0.5f * ((__expf(ls) + d * d) / (1.f + EPSF) - 1.f - ls);
    }
    v = wred64(v);
    if (tid == 0) atomicAdd(&scal[3], v);
  }
}

// ---------------- kl_alpha ---------------------------------------------------
__global__ void k_klalpha(const float* __restrict__ mu, const float* __restrict__ ls,
                          float* __restrict__ scal) {
  int idx = blockIdx.x * 256 + threadIdx.x;
  float v = 0.f;
  if (idx < KDIM * TDIM * EDIM) {
    int t = (idx / EDIM) % TDIM;
    float l = ls[idx], m = mu[idx];
    if (t == 0) v = 0.5f * ((__expf(l) + m * m) / (1.f + EPSF) - 1.f - l);
    else { float d = m - mu[idx - EDIM]; v = 0.5f * ((__expf(l) + d * d) / (DELTAF + EPSF) - 1.f + LOGD - l); }
  }
  v = wred64(v);
  __shared__ float p[4];
  if ((threadIdx.x & 63) == 0) p[threadIdx.x >> 6] = v;
  __syncthreads();
  if (threadIdx.x == 0) atomicAdd(&scal[1], p[0] + p[1] + p[2] + p[3]);
}

// ---------------- time buckets ----------------------------------------------
__global__ void k_bucket(const int* __restrict__ times, int* __restrict__ bcnt,
                         int* __restrict__ bucket) {
  __shared__ int cnt[TDIM];
  int tid = threadIdx.x;  // 128
  if (tid < TDIM) cnt[tid] = 0;
  __syncthreads();
  if (tid < BDIM) {
    int t = times[tid];
    int s = atomicAdd(&cnt[t], 1);
    bucket[t * 128 + s] = tid;
  }
  __syncthreads();
  if (tid < TDIM) bcnt[tid] = cnt[tid];
}

// ---------------- wgt[b][k] = theta[b][k] / Z[t_b*64+k] ---------------------
__global__ void k_wgt(const float* __restrict__ theta, const float* __restrict__ Z,
                      const int* __restrict__ times, float* __restrict__ wgt) {
  int idx = blockIdx.x * 256 + threadIdx.x;  // 6400
  if (idx >= BDIM * 64) return;
  int b = idx >> 6, k = idx & 63;
  float v = 0.f;
  if (k < KDIM) v = theta[b * KDIM + k] / Z[times[b] * 64 + k];
  wgt[idx] = v;
}

// ================= B-stationary MFMA GEMM (both passes) =====================
template <bool PASSB>
__global__ __launch_bounds__(512, 2) void k_gemm(
    const unsigned short* __restrict__ A2, const unsigned short* __restrict__ B2,
    float* __restrict__ Z, const float* __restrict__ wgt,
    const float* __restrict__ bows, const int* __restrict__ bcnt,
    const int* __restrict__ bucket, float* __restrict__ scal) {
  extern __shared__ __align__(16) unsigned short Bs[];  // [128][320] swizzled
  __shared__ float p[8];
  int tid = threadIdx.x, wv = tid >> 6, lane = tid & 63;
  int vbase = blockIdx.x * 128;
  int r15 = lane & 15, gh = lane >> 4, x7 = r15 & 7;

  // ---- stage 80 KB linearly: 80 chunks of 1 KB, 10 per wave
  const unsigned short* gB = B2 + (size_t)vbase * KPAD;
#pragma unroll
  for (int c = 0; c < 10; ++c) {
    int chunk = wv * 10 + c;
    gload_lds16(gB + chunk * 512 + lane * 8, Bs + chunk * 512);
  }
  __syncthreads();

  const unsigned short* Br = Bs + r15 * KPAD;
  float nacc = 0.f;

  for (int jj = 0; jj < 5; ++jj) {
    int q = jj * 8 + wv;  // t-quad owned by this wave this round
    f32x4 acc[4][8];
#pragma unroll
    for (int si = 0; si < 4; ++si)
#pragma unroll
      for (int sj = 0; sj < 8; ++sj) acc[si][sj] = (f32x4){0.f, 0.f, 0.f, 0.f};

    const bf16x8* ab = (const bf16x8*)(A2 + (size_t)(q * 64 + r15) * KPAD) + gh;
#pragma unroll 2
    for (int kk = 0; kk < 10; ++kk) {
      bf16x8 a0 = ab[kk * 4];
      bf16x8 a1 = ab[640 + kk * 4];
      bf16x8 a2 = ab[1280 + kk * 4];
      bf16x8 a3 = ab[1920 + kk * 4];
      int spo = (((kk * 4 + gh) ^ x7) << 3);
#pragma unroll
      for (int sj = 0; sj < 8; ++sj) {
        bf16x8 b = *(const bf16x8*)(Br + sj * 5120 + spo);
        acc[0][sj] = __builtin_amdgcn_mfma_f32_16x16x32_bf16(a0, b, acc[0][sj], 0, 0, 0);
        acc[1][sj] = __builtin_amdgcn_mfma_f32_16x16x32_bf16(a1, b, acc[1][sj], 0, 0, 0);
        acc[2][sj] = __builtin_amdgcn_mfma_f32_16x16x32_bf16(a2, b, acc[2][sj], 0, 0, 0);
        acc[3][sj] = __builtin_amdgcn_mfma_f32_16x16x32_bf16(a3, b, acc[3][sj], 0, 0, 0);
      }
    }

    if (!PASSB) {
      // Z[m] += sum_v exp(logit)
#pragma unroll
      for (int si = 0; si < 4; ++si) {
#pragma unroll
        for (int r = 0; r < 4; ++r) {
          float es = 0.f;
#pragma unroll
          for (int sj = 0; sj < 8; ++sj) {
            int v = vbase + sj * 16 + r15;
            es += (v < VDIM) ? __expf(acc[si][sj][r]) : 0.f;
          }
          es += __shfl_xor(es, 1, 64); es += __shfl_xor(es, 2, 64);
          es += __shfl_xor(es, 4, 64); es += __shfl_xor(es, 8, 64);
          if (r15 == 0) atomicAdd(&Z[q * 64 + si * 16 + gh * 4 + r], es);
        }
      }
    } else {
#pragma unroll
      for (int si = 0; si < 4; ++si)
#pragma unroll
        for (int sj = 0; sj < 8; ++sj)
#pragma unroll
          for (int r = 0; r < 4; ++r) acc[si][sj][r] = __expf(acc[si][sj][r]);
      int cnt = bcnt[q];
      for (int n = 0; n < cnt; ++n) {
        int b = bucket[q * 128 + n];
        float4 w4[4];
#pragma unroll
        for (int si = 0; si < 4; ++si)
          w4[si] = *(const float4*)(wgt + b * 64 + si * 16 + gh * 4);
#pragma unroll
        for (int sj = 0; sj < 8; ++sj) {
          float local = 0.f;
#pragma unroll
          for (int si = 0; si < 4; ++si)
            local += w4[si].x * acc[si][sj][0] + w4[si].y * acc[si][sj][1] +
                     w4[si].z * acc[si][sj][2] + w4[si].w * acc[si][sj][3];
          local += __shfl_xor(local, 16, 64);
          local += __shfl_xor(local, 32, 64);
          int v = vbase + sj * 16 + r15;
          if (lane < 16 && v < VDIM)
            nacc += bows[(size_t)b * VDIM + v] * __logf(local + EPSF);
        }
      }
    }
  }

  if (PASSB) {
    nacc = wred64(nacc);
    if (lane == 0) p[wv] = nacc;
    __syncthreads();
    if (tid == 0)
      atomicAdd(&scal[0], p[0] + p[1] + p[2] + p[3] + p[4] + p[5] + p[6] + p[7]);
  }
}

// ================= fallback-path MFMA kernels (round-1, known-good) =========
__device__ inline void stage_B(const float* __restrict__ we, int vbase,
                               unsigned short* LB, int tid) {
  for (int q = tid; q < VT * 75; q += 256) {
    int vp = q / 75, e4 = (q % 75) * 4;
    float4 w = *(const float4*)(we + (size_t)(vbase + vp) * EDIM + e4);
    unsigned* p32 = (unsigned*)(LB + vp * LBSTR + e4);
    p32[0] = (unsigned)f2bf(w.x) | ((unsigned)f2bf(w.y) << 16);
    p32[1] = (unsigned)f2bf(w.z) | ((unsigned)f2bf(w.w) << 16);
  }
  for (int q = tid; q < VT * 28; q += 256) {
    int vp = q / 28, e = 300 + q % 28;
    LB[vp * LBSTR + e] = 0;
  }
}

__device__ inline void quad_mainloop(const unsigned short* __restrict__ A2,
                                     const unsigned short* LB, int quad, int lane,
                                     f32x4 (&acc)[4][5]) {
  int mrow = quad * 64 + (lane & 15);
  int eoff = (lane >> 4) * 8;
  const bf16x8* ap[4];
#pragma unroll
  for (int ss = 0; ss < 4; ss++)
    ap[ss] = (const bf16x8*)(A2 + (size_t)(mrow + ss * 16) * KPAD + eoff);
  const unsigned short* bp = LB + (lane & 15) * LBSTR + eoff;
#pragma unroll
  for (int kk = 0; kk < 10; kk++) {
    bf16x8 a[4];
#pragma unroll
    for (int ss = 0; ss < 4; ss++) a[ss] = ap[ss][kk * 4];
#pragma unroll
    for (int cf = 0; cf < 5; cf++) {
      bf16x8 b = *(const bf16x8*)(bp + cf * 16 * LBSTR + kk * 32);
#pragma unroll
      for (int ss = 0; ss < 4; ss++)
        acc[ss][cf] = __builtin_amdgcn_mfma_f32_16x16x32_bf16(a[ss], b, acc[ss][cf], 0, 0, 0);
    }
  }
}

__global__ __launch_bounds__(256, 2) void k_passA(const float* __restrict__ we,
                                                  const unsigned short* __restrict__ A2,
                                                  float* __restrict__ Z) {
  __shared__ __align__(16) unsigned short LB[VT * LBSTR];
  int tid = threadIdx.x, vbase = blockIdx.x * VT;
  stage_B(we, vbase, LB, tid);
  __syncthreads();
  int wave = tid >> 6, lane = tid & 63;
  for (int q = wave; q < TDIM; q += 4) {
    f32x4 acc[4][5];
#pragma unroll
    for (int ss = 0; ss < 4; ss++)
#pragma unroll
      for (int cf = 0; cf < 5; cf++) acc[ss][cf] = (f32x4){0.f, 0.f, 0.f, 0.f};
    quad_mainloop(A2, LB, q, lane, acc);
#pragma unroll
    for (int ss = 0; ss < 4; ss++) {
#pragma unroll
      for (int r = 0; r < 4; r++) {
        float s = __expf(acc[ss][0][r]) + __expf(acc[ss][1][r]) + __expf(acc[ss][2][r]) +
                  __expf(acc[ss][3][r]) + __expf(acc[ss][4][r]);
        s += __shfl_xor(s, 1, 64); s += __shfl_xor(s, 2, 64);
        s += __shfl_xor(s, 4, 64); s += __shfl_xor(s, 8, 64);
        if ((lane & 15) == 0)
          atomicAdd(&Z[q * 64 + ss * 16 + (lane >> 4) * 4 + r], s);
      }
    }
  }
}

__global__ __launch_bounds__(256, 2) void k_passB(const float* __restrict__ we,
                                                  const unsigned short* __restrict__ A2,
                                                  const float* __restrict__ wgt,
                                                  const float* __restrict__ bows,
                                                  const int* __restrict__ bcnt,
                                                  const int* __restrict__ bucket,
                                                  float* __restrict__ scal) {
  __shared__ __align__(16) unsigned short LB[VT * LBSTR];
  int tid = threadIdx.x, vbase = blockIdx.x * VT;
  stage_B(we, vbase, LB, tid);
  __syncthreads();
  int wave = tid >> 6, lane = tid & 63;
  float nacc = 0.f;
  for (int t = wave; t < TDIM; t += 4) {
    f32x4 acc[4][5];
#pragma unroll
    for (int ss = 0; ss < 4; ss++)
#pragma unroll
      for (int cf = 0; cf < 5; cf++) acc[ss][cf] = (f32x4){0.f, 0.f, 0.f, 0.f};
    quad_mainloop(A2, LB, t, lane, acc);
#pragma unroll
    for (int ss = 0; ss < 4; ss++)
#pragma unroll
      for (int cf = 0; cf < 5; cf++)
#pragma unroll
        for (int r = 0; r < 4; r++) acc[ss][cf][r] = __expf(acc[ss][cf][r]);
    int cnt = bcnt[t];
    for (int n = 0; n < cnt; n++) {
      int b = bucket[t * 128 + n];
      float4 w[4];
#pragma unroll
      for (int ss = 0; ss < 4; ss++)
        w[ss] = *(const float4*)(wgt + b * 64 + ss * 16 + (lane >> 4) * 4);
#pragma unroll
      for (int cf = 0; cf < 5; cf++) {
        float local = 0.f;
#pragma unroll
        for (int ss = 0; ss < 4; ss++)
          local += w[ss].x * acc[ss][cf][0] + w[ss].y * acc[ss][cf][1] +
                   w[ss].z * acc[ss][cf][2] + w[ss].w * acc[ss][cf][3];
        local += __shfl_xor(local, 16, 64);
        local += __shfl_xor(local, 32, 64);
        int v = vbase + cf * 16 + (lane & 15);
        float contrib = bows[(size_t)b * VDIM + v] * __logf(local + EPSF);
        if (lane < 16) nacc += contrib;
      }
    }
  }
  nacc = wred64(nacc);
  __shared__ float p[4];
  if (lane == 0) p[wave] = nacc;
  __syncthreads();
  if (tid == 0) atomicAdd(&scal[0], p[0] + p[1] + p[2] + p[3]);
}

// ---------------- finalize ---------------------------------------------------
__global__ void k_finalize(const float* __restrict__ scal, float* __restrict__ out) {
  if (threadIdx.x == 0 && blockIdx.x == 0) {
    float nll = -scal[0];
    out[0] = nll + scal[1] + scal[2] + scal[3];
    out[1] = nll;
    out[2] = scal[1];
    out[3] = scal[2];
    out[4] = scal[3];
  }
}

extern "C" void kernel_launch(void* const* d_in, const int* in_sizes, int n_in,
                              void* d_out, int out_size, void* d_ws, size_t ws_size,
                              hipStream_t stream) {
  const float* bows  = (const float*)d_in[0];
  const float* nbows = (const float*)d_in[1];
  const float* rnn   = (const float*)d_in[2];
  const float* wemb  = (const float*)d_in[3];
  const float* mua   = (const float*)d_in[4];
  const float* lsa   = (const float*)d_in[5];
  const float* Wth   = (const float*)d_in[6];
  const float* bth   = (const float*)d_in[7];
  const float* Wmt   = (const float*)d_in[8];
  const float* bmt   = (const float*)d_in[9];
  const float* Wlt   = (const float*)d_in[10];
  const float* blt   = (const float*)d_in[11];
  const float* Wmap  = (const float*)d_in[12];
  const float* bmap  = (const float*)d_in[13];
  const float* Wih   = (const float*)d_in[14];
  const float* Whh   = (const float*)d_in[15];
  const float* bihp  = (const float*)d_in[16];
  const float* bhhp  = (const float*)d_in[17];
  const float* Wme   = (const float*)d_in[18];
  const float* bme   = (const float*)d_in[19];
  const float* Wle   = (const float*)d_in[20];
  const float* ble   = (const float*)d_in[21];
  const int* times   = (const int*)d_in[22];

  float* ws = (float*)d_ws;
  float* scal  = ws;                 // 8
  float* Z     = ws + 8;             // 2560
  float* hpre  = ws + 2568;          // 80000
  float* omap  = ws + 82568;         // 8000   (end of zeroed region: 90568 floats)
  float* xa    = ws + 90568;         // 8000
  float* xb    = ws + 98568;         // 8000
  float* lout  = ws + 106568;        // 8000
  float* Gin   = ws + 114568;        // 32000
  unsigned* WhhT = (unsigned*)(ws + 146568);   // 240000
  float* etas  = ws + 386568;        // 2000
  float* theta = ws + 388568;        // 5000
  float* wgt   = ws + 393568;        // 6400
  int* bcnt    = (int*)(ws + 399968);          // 64
  int* bucket  = (int*)(ws + 400032);          // 5120
  unsigned short* A2 = (unsigned short*)(ws + 405152);  // 819200 ushorts -> ends 814752
  unsigned short* B2 = (unsigned short*)(ws + 814752);  // 30080*320 ushorts = 19.25 MB

  // fast path needs ws up to byte offset 814752*4 + 19251200 = 22510208
  bool fast = ws_size >= 23000000u;

  if (fast) {
    static bool attr_set = false;
    if (!attr_set) {
      auto kA = k_gemm<false>;
      auto kB = k_gemm<true>;
      (void)hipFuncSetAttribute((const void*)kA,
                                hipFuncAttributeMaxDynamicSharedMemorySize, GEMM_LDS);
      (void)hipFuncSetAttribute((const void*)kB,
                                hipFuncAttributeMaxDynamicSharedMemorySize, GEMM_LDS);
      attr_set = true;
    }
  }

  hipMemsetAsync(ws, 0, 90568 * sizeof(float), stream);

  k_prep_A2<<<3200, 256, 0, stream>>>(mua, A2);
  if (fast) k_prep_B<<<9400, 256, 0, stream>>>(wemb, B2);
  k_map2<<<dim3(313, 2), 256, 0, stream>>>(rnn, Wmap, bmap, omap);
  k_wt<<<300, 256, 0, stream>>>(Whh, WhhT);
  k_bucket<<<1, 128, 0, stream>>>(times, bcnt, bucket);

  if (fast)
    k_gemm<false><<<235, 512, GEMM_LDS, stream>>>(A2, B2, Z, nullptr, nullptr,
                                                  nullptr, nullptr, nullptr);
  else
    k_passA<<<NBLK_V, 256, 0, stream>>>(wemb, A2, Z);

  k_igemm<<<400, 256, 0, stream>>>(Wih, bihp, bhhp, omap, Gin, 0);
  k_rec<<<1, 1024, 0, stream>>>(WhhT, Gin, xa);
  k_igemm<<<400, 256, 0, stream>>>(Wih, bihp, bhhp, xa, Gin, 1);
  k_rec<<<1, 1024, 0, stream>>>(WhhT + 100 * 800, Gin, xb);
  k_igemm<<<400, 256, 0, stream>>>(Wih, bihp, bhhp, xb, Gin, 2);
  k_rec<<<1, 1024, 0, stream>>>(WhhT + 200 * 800, Gin, lout);

  k_eta<<<1, 512, 0, stream>>>(Wme, bme, Wle, ble, lout, etas, scal);
  k_hpre<<<dim3(13, 47), 256, 0, stream>>>(nbows, Wth, hpre);
  k_theta<<<100, 256, 0, stream>>>(hpre, bth, Wth, Wmt, bmt, Wlt, blt, etas, times, theta, scal);
  k_wgt<<<25, 256, 0, stream>>>(theta, Z, times, wgt);
  k_klalpha<<<2344, 256, 0, stream>>>(mua, lsa, scal);

  if (fast)
    k_gemm<true><<<235, 512, GEMM_LDS, stream>>>(A2, B2, Z, wgt, bows, bcnt,
                                                 bucket, scal);
  else
    k_passB<<<NBLK_V, 256, 0, stream>>>(wemb, A2, wgt, bows, bcnt, bucket, scal);

  k_finalize<<<1, 64, 0, stream>>>(scal, (float*)d_out);
}

// Round 5
// 1576.742 us; speedup vs baseline: 1.3293x; 1.0966x over previous
//
#include <hip/hip_runtime.h>

#define KDIM 50
#define TDIM 40
#define VDIM 30000
#define THDIM 800
#define EHDIM 200
#define EDIM 300
#define BDIM 100
#define DELTAF 0.005f
#define EPSF 1e-6f
#define LOGD (-5.2983174f)
#define MROWS 2560   // TDIM*64 rows for MFMA A operand
#define KPAD 320     // E padded to 320
#define VROWS 30080  // V padded to 235*128
#define VT 80        // v-tile per MFMA block (fallback path)
#define NBLK_V 375   // 30000/80 (fallback path)
#define LBSTR 328    // fallback LDS B-tile row stride
#define GEMM_LDS 81920  // 128 rows * 320 cols * 2B

typedef __attribute__((ext_vector_type(8))) short bf16x8;
typedef __attribute__((ext_vector_type(4))) float f32x4;
typedef unsigned int u32;

__device__ inline float wred64(float v) {
  v += __shfl_xor(v, 32, 64); v += __shfl_xor(v, 16, 64);
  v += __shfl_xor(v, 8, 64);  v += __shfl_xor(v, 4, 64);
  v += __shfl_xor(v, 2, 64);  v += __shfl_xor(v, 1, 64);
  return v;
}

__device__ inline unsigned short f2bf(float f) {
  union { float f; unsigned u; } x; x.f = f;
  unsigned r = x.u + 0x7fffu + ((x.u >> 16) & 1u);
  return (unsigned short)(r >> 16);
}

__device__ inline void gload_lds16(const void* g, void* l) {
  __builtin_amdgcn_global_load_lds(
      (const __attribute__((address_space(1))) u32*)g,
      (__attribute__((address_space(3))) u32*)l, 16, 0, 0);
}

// ---------------- A2 prep: mu_q_alpha[k][t][e] -> bf16 A2[t*64+k][e<320] ----
__global__ void k_prep_A2(const float* __restrict__ mu_q, unsigned short* __restrict__ A2) {
  int idx = blockIdx.x * 256 + threadIdx.x;   // 2560*320 = 819200
  if (idx >= MROWS * KPAD) return;
  int m = idx / KPAD, e = idx % KPAD;
  int t = m >> 6, kp = m & 63;
  float v = 0.f;
  if (kp < KDIM && e < EDIM) v = mu_q[(kp * TDIM + t) * EDIM + e];
  A2[idx] = f2bf(v);
}

// ---------------- B2 prep: word_emb fp32 [30000][300] -> bf16 [30080][320] --
// PRE-SWIZZLED: 16B slot s (e>>3) stored at physical slot s ^ (v&7), so the
// GEMM's linear global_load_lds staging + XOR'd ds_read_b128 is bank-balanced.
__global__ void k_prep_B(const float* __restrict__ we, unsigned short* __restrict__ B2) {
  int idx = blockIdx.x * 256 + threadIdx.x;   // 30080*80 = 2406400
  if (idx >= VROWS * 80) return;
  int v = idx / 80, e4 = (idx % 80) * 4;
  ushort4 o = {0, 0, 0, 0};
  if (v < VDIM && e4 < EDIM) {
    float4 w = *(const float4*)(we + (size_t)v * EDIM + e4);
    o.x = f2bf(w.x); o.y = f2bf(w.y); o.z = f2bf(w.z); o.w = f2bf(w.w);
  }
  int dcol = (((e4 >> 3) ^ (v & 7)) << 3) | (e4 & 7);
  *(ushort4*)(B2 + (size_t)v * KPAD + dcol) = o;
}

// ---------------- out_map = rnn_inp @ W_map^T + b_map  [40,200] -------------
#define MP_VS 96
#define RS_STR 44
#define WS_STR 104
__global__ __launch_bounds__(256) void k_map2(const float* __restrict__ rnn,
                                              const float* __restrict__ Wmap,
                                              const float* __restrict__ bmap,
                                              float* __restrict__ omap) {
  __shared__ __align__(16) float rs[MP_VS * RS_STR];
  __shared__ __align__(16) float wsb[MP_VS * WS_STR];
  int c = blockIdx.x, eh = blockIdx.y;
  int v0 = c * MP_VS, e0 = eh * 100;
  int tid = threadIdx.x;
  for (int idx = tid; idx < TDIM * MP_VS; idx += 256) {
    int t = idx / MP_VS, vv = idx % MP_VS;
    int v = v0 + vv;
    rs[vv * RS_STR + t] = (v < VDIM) ? rnn[(size_t)t * VDIM + v] : 0.f;
  }
  for (int idx = tid; idx < 100 * MP_VS; idx += 256) {
    int e = idx / MP_VS, vv = idx % MP_VS;
    int v = v0 + vv;
    wsb[vv * WS_STR + e] = (v < VDIM) ? Wmap[(size_t)(e0 + e) * VDIM + v] : 0.f;
  }
  __syncthreads();
  if (tid >= 250) return;
  int eg = tid / 10, tg = tid % 10;
  float acc[4][4];
#pragma unroll
  for (int i = 0; i < 4; i++)
#pragma unroll
    for (int j = 0; j < 4; j++) acc[i][j] = 0.f;
  int nvv = min(MP_VS, VDIM - v0);
  for (int vv = 0; vv < nvv; vv++) {
    float4 wv = *(const float4*)&wsb[vv * WS_STR + eg * 4];
    float4 rv = *(const float4*)&rs[vv * RS_STR + tg * 4];
    float wa[4] = {wv.x, wv.y, wv.z, wv.w};
    float ra[4] = {rv.x, rv.y, rv.z, rv.w};
#pragma unroll
    for (int i = 0; i < 4; i++)
#pragma unroll
      for (int j = 0; j < 4; j++) acc[i][j] += wa[i] * ra[j];
  }
#pragma unroll
  for (int i = 0; i < 4; i++) {
    int e = e0 + eg * 4 + i;
#pragma unroll
    for (int j = 0; j < 4; j++) {
      int t = tg * 4 + j;
      float a = acc[i][j];
      if (c == 0) a += bmap[e];
      atomicAdd(&omap[t * EHDIM + e], a);
    }
  }
}

// ---------------- Whh transpose+pack to bf16 pairs: WhhT[l][jp][i] ----------
__global__ void k_wt(const float* __restrict__ Whh, unsigned* __restrict__ WhhT) {
  int l = blockIdx.x / 100, jp = blockIdx.x % 100;
  for (int i = threadIdx.x; i < THDIM; i += 256) {
    float w0 = Whh[(l * THDIM + i) * EHDIM + 2 * jp];
    float w1 = Whh[(l * THDIM + i) * EHDIM + 2 * jp + 1];
    WhhT[(l * 100 + jp) * THDIM + i] = (unsigned)f2bf(w0) | ((unsigned)f2bf(w1) << 16);
  }
}

// ---------------- LSTM input GEMM: G[t][i] = Wih[l][i]·x[t] + bih + bhh -----
__global__ void k_igemm(const float* __restrict__ Wih, const float* __restrict__ bih,
                        const float* __restrict__ bhh, const float* __restrict__ x,
                        float* __restrict__ G, int l) {
  int wave = threadIdx.x >> 6, lane = threadIdx.x & 63;
  int d0 = blockIdx.x * 80 + wave * 20;
  for (int n = 0; n < 20; n++) {
    int d = d0 + n;
    int t = d / THDIM, i = d % THDIM;
    const float* row = Wih + (l * THDIM + i) * EHDIM;
    const float* xt = x + t * EHDIM;
    float acc = 0.f;
#pragma unroll
    for (int m = 0; m < 4; m++) { int j = m * 64 + lane; if (j < EHDIM) acc += row[j] * xt[j]; }
    acc = wred64(acc);
    if (lane == 0) G[t * THDIM + i] = acc + bih[l * THDIM + i] + bhh[l * THDIM + i];
  }
}

// ---------------- LSTM recurrence (single block, streams bf16 WhhT) ---------
__global__ __launch_bounds__(1024) void k_rec(const unsigned* __restrict__ WT,
                                              const float* __restrict__ G,
                                              float* __restrict__ xout) {
  __shared__ __align__(16) float h[EHDIM];
  __shared__ float g[THDIM];
  int tid = threadIdx.x;
  if (tid < EHDIM) h[tid] = 0.f;
  float c = 0.f;
  __syncthreads();
  for (int t = 0; t < TDIM; t++) {
    if (tid < THDIM) {
      float acc = G[t * THDIM + tid];
      const unsigned* wp = WT + tid;
      const float4* h4 = (const float4*)h;
      for (int q = 0; q < 50; q++) {
        float4 hq = h4[q];
        unsigned wa = wp[(2 * q) * THDIM];
        unsigned wb = wp[(2 * q + 1) * THDIM];
        union { unsigned u; float f; } la, ha, lb, hb;
        la.u = wa << 16; ha.u = wa & 0xffff0000u;
        lb.u = wb << 16; hb.u = wb & 0xffff0000u;
        acc += la.f * hq.x + ha.f * hq.y + lb.f * hq.z + hb.f * hq.w;
      }
      g[tid] = acc;
    }
    __syncthreads();
    if (tid < EHDIM) {
      float si = 1.f / (1.f + __expf(-g[tid]));
      float sf = 1.f / (1.f + __expf(-g[200 + tid]));
      float sg = tanhf(g[400 + tid]);
      float so = 1.f / (1.f + __expf(-g[600 + tid]));
      c = sf * c + si * sg;
      float hn = so * tanhf(c);
      xout[t * EHDIM + tid] = hn;
      h[tid] = hn;
    }
    __syncthreads();
  }
}

// ---------------- eta: parallel part  MhLh[t][j] = W[:, :200]·h_t + b -------
// j<50: mu row j (Wme,bme); j in 50..99: ls row j-50 (Wle,ble). 40 blocks.
__global__ void k_eta_pre(const float* __restrict__ Wmu, const float* __restrict__ bmu,
                          const float* __restrict__ Wls, const float* __restrict__ bls,
                          const float* __restrict__ lout, float* __restrict__ MhLh) {
  int t = blockIdx.x;
  int wave = threadIdx.x >> 6, lane = threadIdx.x & 63;
  const float* xt = lout + t * EHDIM;
  for (int jb = wave; jb < 2 * KDIM; jb += 4) {
    const float* row = (jb < KDIM) ? (Wmu + jb * 250) : (Wls + (jb - KDIM) * 250);
    float acc = 0.f;
#pragma unroll
    for (int m = 0; m < 4; m++) {
      int j = m * 64 + lane;
      if (j < EHDIM) acc += row[j] * xt[j];
    }
    acc = wred64(acc);
    if (lane == 0) {
      float b = (jb < KDIM) ? bmu[jb] : bls[jb - KDIM];
      MhLh[t * 128 + jb] = acc + b;
    }
  }
}

// ---------------- eta: sequential chain (1 wave, weights in registers) ------
// eta_t[j] = MhLh[t][j] + W[:,200:250]·eta_{t-1}; kl accumulated per step.
__global__ void k_eta_chain(const float* __restrict__ Wmu, const float* __restrict__ Wls,
                            const float* __restrict__ MhLh, float* __restrict__ etas,
                            float* __restrict__ scal) {
  __shared__ float eta[64];
  int j = threadIdx.x;  // 64 = one wave
  float wm[KDIM], wl[KDIM];
  if (j < KDIM) {
#pragma unroll
    for (int k = 0; k < KDIM; k++) {
      wm[k] = Wmu[j * 250 + EHDIM + k];
      wl[k] = Wls[j * 250 + EHDIM + k];
    }
  } else {
#pragma unroll
    for (int k = 0; k < KDIM; k++) { wm[k] = 0.f; wl[k] = 0.f; }
  }
  eta[j] = 0.f;
  float ep = 0.f;   // eta_{t-1}[j]
  float kl = 0.f;
  __syncthreads();
  for (int t = 0; t < TDIM; t++) {
    float am = 0.f, al = 0.f;
#pragma unroll
    for (int k = 0; k < KDIM; k++) {
      float e = eta[k];          // broadcast read
      am += wm[k] * e;
      al += wl[k] * e;
    }
    float v = 0.f, mu = 0.f;
    if (j < KDIM) {
      mu = MhLh[t * 128 + j] + am;
      float ls = MhLh[t * 128 + KDIM + j] + al;
      float d = mu - ep;
      if (t == 0) v = 0.5f * ((__expf(ls) + mu * mu) / (1.f + EPSF) - 1.f - ls);
      else        v = 0.5f * ((__expf(ls) + d * d) / (DELTAF + EPSF) - 1.f + LOGD - ls);
      etas[t * KDIM + j] = mu;
    }
    v = wred64(v);
    if (j == 0) kl += v;
    __syncthreads();
    if (j < KDIM) { eta[j] = mu; ep = mu; }
    __syncthreads();
  }
  if (j == 0) scal[2] = kl;
}

// ---------------- h_pre = nb @ W_theta[:, :V]^T  (MFMA, bf16 hi+lo split) ---
#define HPM_STR 40
__global__ __launch_bounds__(256, 2) void k_hpre(const float* __restrict__ nb,
                                                 const float* __restrict__ Wth,
                                                 float* __restrict__ h_pre) {
  __shared__ __align__(16) unsigned short Ahi[64 * HPM_STR];
  __shared__ __align__(16) unsigned short Alo[64 * HPM_STR];
  __shared__ __align__(16) unsigned short Bhi[112 * HPM_STR];
  __shared__ __align__(16) unsigned short Blo[112 * HPM_STR];
  int tid = threadIdx.x, wv = tid >> 6, lane = tid & 63;
  int r15 = lane & 15, gh = lane >> 4;
  int mt = blockIdx.x;                        // 13 m-tiles of 64 TH rows
  int s0 = blockIdx.y * 20;
  int s1 = min(s0 + 20, 938);                 // 938 K-steps of 32 cover 30016
  f32x4 acc[7];
#pragma unroll
  for (int j = 0; j < 7; ++j) acc[j] = (f32x4){0.f, 0.f, 0.f, 0.f};
  int srow = tid >> 3, sk4 = (tid & 7) * 4;   // float col within 32-k tile
  for (int s = s0; s < s1; ++s) {
    int k = s * 32 + sk4;
    bool kok = (k + 3) < VDIM;                // 30000%4==0: never straddles
    float4 av[2], bv[4];
#pragma unroll
    for (int it = 0; it < 2; ++it) {
      int th = mt * 64 + srow + it * 32;
      float4 v = {0.f, 0.f, 0.f, 0.f};
      if (th < THDIM && kok) {
        const float* p = Wth + (size_t)th * 30050 + k;  // 8B-aligned only
        float2 p0 = *(const float2*)p;
        float2 p1 = *(const float2*)(p + 2);
        v.x = p0.x; v.y = p0.y; v.z = p1.x; v.w = p1.y;
      }
      av[it] = v;
    }
#pragma unroll
    for (int it = 0; it < 4; ++it) {
      int b = srow + it * 32;
      float4 v = {0.f, 0.f, 0.f, 0.f};
      if (b < BDIM && kok) v = *(const float4*)(nb + (size_t)b * VDIM + k);
      bv[it] = v;
    }
    __syncthreads();   // all waves done reading LDS from previous step
#pragma unroll
    for (int it = 0; it < 2; ++it) {
      int row = srow + it * 32;
      float fa[4] = {av[it].x, av[it].y, av[it].z, av[it].w};
      unsigned short hh[4], ll[4];
#pragma unroll
      for (int u = 0; u < 4; ++u) {
        unsigned short hv = f2bf(fa[u]);
        union { unsigned uu; float f; } uf; uf.uu = (unsigned)hv << 16;
        hh[u] = hv; ll[u] = f2bf(fa[u] - uf.f);
      }
      *(ushort4*)(Ahi + row * HPM_STR + sk4) = (ushort4){hh[0], hh[1], hh[2], hh[3]};
      *(ushort4*)(Alo + row * HPM_STR + sk4) = (ushort4){ll[0], ll[1], ll[2], ll[3]};
    }
#pragma unroll
    for (int it = 0; it < 4; ++it) {
      int row = srow + it * 32;
      if (row < 112) {
        float fb[4] = {bv[it].x, bv[it].y, bv[it].z, bv[it].w};
        unsigned short hh[4], ll[4];
#pragma unroll
        for (int u = 0; u < 4; ++u) {
          unsigned short hv = f2bf(fb[u]);
          union { unsigned uu; float f; } uf; uf.uu = (unsigned)hv << 16;
          hh[u] = hv; ll[u] = f2bf(fb[u] - uf.f);
        }
        *(ushort4*)(Bhi + row * HPM_STR + sk4) = (ushort4){hh[0], hh[1], hh[2], hh[3]};
        *(ushort4*)(Blo + row * HPM_STR + sk4) = (ushort4){ll[0], ll[1], ll[2], ll[3]};
      }
    }
    __syncthreads();
    bf16x8 ah = *(const bf16x8*)(Ahi + (wv * 16 + r15) * HPM_STR + gh * 8);
    bf16x8 al = *(const bf16x8*)(Alo + (wv * 16 + r15) * HPM_STR + gh * 8);
#pragma unroll
    for (int sj = 0; sj < 7; ++sj) {
      bf16x8 bh = *(const bf16x8*)(Bhi + (sj * 16 + r15) * HPM_STR + gh * 8);
      bf16x8 bl = *(const bf16x8*)(Blo + (sj * 16 + r15) * HPM_STR + gh * 8);
      acc[sj] = __builtin_amdgcn_mfma_f32_16x16x32_bf16(ah, bh, acc[sj], 0, 0, 0);
      acc[sj] = __builtin_amdgcn_mfma_f32_16x16x32_bf16(ah, bl, acc[sj], 0, 0, 0);
      acc[sj] = __builtin_amdgcn_mfma_f32_16x16x32_bf16(al, bh, acc[sj], 0, 0, 0);
    }
  }
#pragma unroll
  for (int sj = 0; sj < 7; ++sj) {
    int b = sj * 16 + r15;
    if (b >= BDIM) continue;
#pragma unroll
    for (int r = 0; r < 4; ++r) {
      int th = mt * 64 + wv * 16 + gh * 4 + r;
      if (th < THDIM) atomicAdd(&h_pre[b * THDIM + th], acc[sj][r]);
    }
  }
}

// ---------------- theta path: tanh, softmax, kl_theta -----------------------
__global__ void k_theta(const float* __restrict__ hpre, const float* __restrict__ bth,
                        const float* __restrict__ Wth, const float* __restrict__ Wmt,
                        const float* __restrict__ bmt, const float* __restrict__ Wlt,
                        const float* __restrict__ blt, const float* __restrict__ etas,
                        const int* __restrict__ times, float* __restrict__ theta,
                        float* __restrict__ scal) {
  __shared__ float et[KDIM];
  __shared__ float hl[THDIM];
  __shared__ float mu_s[KDIM], ls_s[KDIM];
  int b = blockIdx.x, tid = threadIdx.x;
  if (tid < KDIM) et[tid] = etas[times[b] * KDIM + tid];
  __syncthreads();
  for (int th = tid; th < THDIM; th += 256) {
    float acc = hpre[b * THDIM + th] + bth[th];
    const float* wrow = Wth + (size_t)th * 30050 + VDIM;
#pragma unroll 10
    for (int k = 0; k < KDIM; k++) acc += et[k] * wrow[k];
    hl[th] = tanhf(acc);
  }
  __syncthreads();
  int wave = tid >> 6, lane = tid & 63;
  for (int jb = wave; jb < 2 * KDIM; jb += 4) {
    const float* row = (jb < KDIM) ? (Wmt + jb * THDIM) : (Wlt + (jb - KDIM) * THDIM);
    float acc = 0.f;
#pragma unroll
    for (int m = 0; m < 13; m++) { int j = m * 64 + lane; if (j < THDIM) acc += row[j] * hl[j]; }
    acc = wred64(acc);
    if (lane == 0) {
      if (jb < KDIM) mu_s[jb] = acc + bmt[jb];
      else ls_s[jb - KDIM] = acc + blt[jb - KDIM];
    }
  }
  __syncthreads();
  if (tid < 64) {
    float m = (tid < KDIM) ? mu_s[tid] : -1e30f;
    float mx = m;
#pragma unroll
    for (int o = 32; o >= 1; o >>= 1) mx = fmaxf(mx, __shfl_xor(mx, o, 64));
    float e = (tid < KDIM) ? __expf(m - mx) : 0.f;
    float s = wred64(e);
    if (tid < KDIM) theta[b * KDIM + tid] = e / s;
    float v = 0.f;
    if (tid < KDIM) {
      float ls = ls_s[tid];
      float d = mu_s[tid] - et[tid];
      v = 0.5f * ((__expf(ls) + d * d) / (1.f + EPSF) - 1.f - ls);
    }
    v = wred64(v);
    if (tid == 0) atomicAdd(&scal[3], v);
  }
}

// ---------------- kl_alpha ---------------------------------------------------
__global__ void k_klalpha(const float* __restrict__ mu, const float* __restrict__ ls,
                          float* __restrict__ scal) {
  int idx = blockIdx.x * 256 + threadIdx.x;
  float v = 0.f;
  if (idx < KDIM * TDIM * EDIM) {
    int t = (idx / EDIM) % TDIM;
    float l = ls[idx], m = mu[idx];
    if (t == 0) v = 0.5f * ((__expf(l) + m * m) / (1.f + EPSF) - 1.f - l);
    else { float d = m - mu[idx - EDIM]; v = 0.5f * ((__expf(l) + d * d) / (DELTAF + EPSF) - 1.f + LOGD - l); }
  }
  v = wred64(v);
  __shared__ float p[4];
  if ((threadIdx.x & 63) == 0) p[threadIdx.x >> 6] = v;
  __syncthreads();
  if (threadIdx.x == 0) atomicAdd(&scal[1], p[0] + p[1] + p[2] + p[3]);
}

// ---------------- time buckets ----------------------------------------------
__global__ void k_bucket(const int* __restrict__ times, int* __restrict__ bcnt,
                         int* __restrict__ bucket) {
  __shared__ int cnt[TDIM];
  int tid = threadIdx.x;  // 128
  if (tid < TDIM) cnt[tid] = 0;
  __syncthreads();
  if (tid < BDIM) {
    int t = times[tid];
    int s = atomicAdd(&cnt[t], 1);
    bucket[t * 128 + s] = tid;
  }
  __syncthreads();
  if (tid < TDIM) bcnt[tid] = cnt[tid];
}

// ---------------- wgt[b][k] = theta[b][k] / Z[t_b*64+k] ---------------------
__global__ void k_wgt(const float* __restrict__ theta, const float* __restrict__ Z,
                      const int* __restrict__ times, float* __restrict__ wgt) {
  int idx = blockIdx.x * 256 + threadIdx.x;  // 6400
  if (idx >= BDIM * 64) return;
  int b = idx >> 6, k = idx & 63;
  float v = 0.f;
  if (k < KDIM) v = theta[b * KDIM + k] / Z[times[b] * 64 + k];
  wgt[idx] = v;
}

// ================= B-stationary MFMA GEMM (both passes) =====================
template <bool PASSB>
__global__ __launch_bounds__(512, 2) void k_gemm(
    const unsigned short* __restrict__ A2, const unsigned short* __restrict__ B2,
    float* __restrict__ Z, const float* __restrict__ wgt,
    const float* __restrict__ bows, const int* __restrict__ bcnt,
    const int* __restrict__ bucket, float* __restrict__ scal) {
  extern __shared__ __align__(16) unsigned short Bs[];  // [128][320] swizzled
  __shared__ float p[8];
  int tid = threadIdx.x, wv = tid >> 6, lane = tid & 63;
  int vbase = blockIdx.x * 128;
  int r15 = lane & 15, gh = lane >> 4, x7 = r15 & 7;

  // ---- stage 80 KB linearly: 80 chunks of 1 KB, 10 per wave
  const unsigned short* gB = B2 + (size_t)vbase * KPAD;
#pragma unroll
  for (int c = 0; c < 10; ++c) {
    int chunk = wv * 10 + c;
    gload_lds16(gB + chunk * 512 + lane * 8, Bs + chunk * 512);
  }
  __syncthreads();

  const unsigned short* Br = Bs + r15 * KPAD;
  float nacc = 0.f;

  for (int jj = 0; jj < 5; ++jj) {
    int q = jj * 8 + wv;  // t-quad owned by this wave this round
    f32x4 acc[4][8];
#pragma unroll
    for (int si = 0; si < 4; ++si)
#pragma unroll
      for (int sj = 0; sj < 8; ++sj) acc[si][sj] = (f32x4){0.f, 0.f, 0.f, 0.f};

    const bf16x8* ab = (const bf16x8*)(A2 + (size_t)(q * 64 + r15) * KPAD) + gh;
#pragma unroll 2
    for (int kk = 0; kk < 10; ++kk) {
      bf16x8 a0 = ab[kk * 4];
      bf16x8 a1 = ab[640 + kk * 4];
      bf16x8 a2 = ab[1280 + kk * 4];
      bf16x8 a3 = ab[1920 + kk * 4];
      int spo = (((kk * 4 + gh) ^ x7) << 3);
#pragma unroll
      for (int sj = 0; sj < 8; ++sj) {
        bf16x8 b = *(const bf16x8*)(Br + sj * 5120 + spo);
        acc[0][sj] = __builtin_amdgcn_mfma_f32_16x16x32_bf16(a0, b, acc[0][sj], 0, 0, 0);
        acc[1][sj] = __builtin_amdgcn_mfma_f32_16x16x32_bf16(a1, b, acc[1][sj], 0, 0, 0);
        acc[2][sj] = __builtin_amdgcn_mfma_f32_16x16x32_bf16(a2, b, acc[2][sj], 0, 0, 0);
        acc[3][sj] = __builtin_amdgcn_mfma_f32_16x16x32_bf16(a3, b, acc[3][sj], 0, 0, 0);
      }
    }

    if (!PASSB) {
      // Z[m] += sum_v exp(logit)
#pragma unroll
      for (int si = 0; si < 4; ++si) {
#pragma unroll
        for (int r = 0; r < 4; ++r) {
          float es = 0.f;
#pragma unroll
          for (int sj = 0; sj < 8; ++sj) {
            int v = vbase + sj * 16 + r15;
            es += (v < VDIM) ? __expf(acc[si][sj][r]) : 0.f;
          }
          es += __shfl_xor(es, 1, 64); es += __shfl_xor(es, 2, 64);
          es += __shfl_xor(es, 4, 64); es += __shfl_xor(es, 8, 64);
          if (r15 == 0) atomicAdd(&Z[q * 64 + si * 16 + gh * 4 + r], es);
        }
      }
    } else {
#pragma unroll
      for (int si = 0; si < 4; ++si)
#pragma unroll
        for (int sj = 0; sj < 8; ++sj)
#pragma unroll
          for (int r = 0; r < 4; ++r) acc[si][sj][r] = __expf(acc[si][sj][r]);
      int cnt = bcnt[q];
      for (int n = 0; n < cnt; ++n) {
        int b = bucket[q * 128 + n];
        float4 w4[4];
#pragma unroll
        for (int si = 0; si < 4; ++si)
          w4[si] = *(const float4*)(wgt + b * 64 + si * 16 + gh * 4);
#pragma unroll
        for (int sj = 0; sj < 8; ++sj) {
          float local = 0.f;
#pragma unroll
          for (int si = 0; si < 4; ++si)
            local += w4[si].x * acc[si][sj][0] + w4[si].y * acc[si][sj][1] +
                     w4[si].z * acc[si][sj][2] + w4[si].w * acc[si][sj][3];
          local += __shfl_xor(local, 16, 64);
          local += __shfl_xor(local, 32, 64);
          int v = vbase + sj * 16 + r15;
          if (lane < 16 && v < VDIM)
            nacc += bows[(size_t)b * VDIM + v] * __logf(local + EPSF);
        }
      }
    }
  }

  if (PASSB) {
    nacc = wred64(nacc);
    if (lane == 0) p[wv] = nacc;
    __syncthreads();
    if (tid == 0)
      atomicAdd(&scal[0], p[0] + p[1] + p[2] + p[3] + p[4] + p[5] + p[6] + p[7]);
  }
}

// ================= fallback-path MFMA kernels (round-1, known-good) =========
__device__ inline void stage_B(const float* __restrict__ we, int vbase,
                               unsigned short* LB, int tid) {
  for (int q = tid; q < VT * 75; q += 256) {
    int vp = q / 75, e4 = (q % 75) * 4;
    float4 w = *(const float4*)(we + (size_t)(vbase + vp) * EDIM + e4);
    unsigned* p32 = (unsigned*)(LB + vp * LBSTR + e4);
    p32[0] = (unsigned)f2bf(w.x) | ((unsigned)f2bf(w.y) << 16);
    p32[1] = (unsigned)f2bf(w.z) | ((unsigned)f2bf(w.w) << 16);
  }
  for (int q = tid; q < VT * 28; q += 256) {
    int vp = q / 28, e = 300 + q % 28;
    LB[vp * LBSTR + e] = 0;
  }
}

__device__ inline void quad_mainloop(const unsigned short* __restrict__ A2,
                                     const unsigned short* LB, int quad, int lane,
                                     f32x4 (&acc)[4][5]) {
  int mrow = quad * 64 + (lane & 15);
  int eoff = (lane >> 4) * 8;
  const bf16x8* ap[4];
#pragma unroll
  for (int ss = 0; ss < 4; ss++)
    ap[ss] = (const bf16x8*)(A2 + (size_t)(mrow + ss * 16) * KPAD + eoff);
  const unsigned short* bp = LB + (lane & 15) * LBSTR + eoff;
#pragma unroll
  for (int kk = 0; kk < 10; kk++) {
    bf16x8 a[4];
#pragma unroll
    for (int ss = 0; ss < 4; ss++) a[ss] = ap[ss][kk * 4];
#pragma unroll
    for (int cf = 0; cf < 5; cf++) {
      bf16x8 b = *(const bf16x8*)(bp + cf * 16 * LBSTR + kk * 32);
#pragma unroll
      for (int ss = 0; ss < 4; ss++)
        acc[ss][cf] = __builtin_amdgcn_mfma_f32_16x16x32_bf16(a[ss], b, acc[ss][cf], 0, 0, 0);
    }
  }
}

__global__ __launch_bounds__(256, 2) void k_passA(const float* __restrict__ we,
                                                  const unsigned short* __restrict__ A2,
                                                  float* __restrict__ Z) {
  __shared__ __align__(16) unsigned short LB[VT * LBSTR];
  int tid = threadIdx.x, vbase = blockIdx.x * VT;
  stage_B(we, vbase, LB, tid);
  __syncthreads();
  int wave = tid >> 6, lane = tid & 63;
  for (int q = wave; q < TDIM; q += 4) {
    f32x4 acc[4][5];
#pragma unroll
    for (int ss = 0; ss < 4; ss++)
#pragma unroll
      for (int cf = 0; cf < 5; cf++) acc[ss][cf] = (f32x4){0.f, 0.f, 0.f, 0.f};
    quad_mainloop(A2, LB, q, lane, acc);
#pragma unroll
    for (int ss = 0; ss < 4; ss++) {
#pragma unroll
      for (int r = 0; r < 4; r++) {
        float s = __expf(acc[ss][0][r]) + __expf(acc[ss][1][r]) + __expf(acc[ss][2][r]) +
                  __expf(acc[ss][3][r]) + __expf(acc[ss][4][r]);
        s += __shfl_xor(s, 1, 64); s += __shfl_xor(s, 2, 64);
        s += __shfl_xor(s, 4, 64); s += __shfl_xor(s, 8, 64);
        if ((lane & 15) == 0)
          atomicAdd(&Z[q * 64 + ss * 16 + (lane >> 4) * 4 + r], s);
      }
    }
  }
}

__global__ __launch_bounds__(256, 2) void k_passB(const float* __restrict__ we,
                                                  const unsigned short* __restrict__ A2,
                                                  const float* __restrict__ wgt,
                                                  const float* __restrict__ bows,
                                                  const int* __restrict__ bcnt,
                                                  const int* __restrict__ bucket,
                                                  float* __restrict__ scal) {
  __shared__ __align__(16) unsigned short LB[VT * LBSTR];
  int tid = threadIdx.x, vbase = blockIdx.x * VT;
  stage_B(we, vbase, LB, tid);
  __syncthreads();
  int wave = tid >> 6, lane = tid & 63;
  float nacc = 0.f;
  for (int t = wave; t < TDIM; t += 4) {
    f32x4 acc[4][5];
#pragma unroll
    for (int ss = 0; ss < 4; ss++)
#pragma unroll
      for (int cf = 0; cf < 5; cf++) acc[ss][cf] = (f32x4){0.f, 0.f, 0.f, 0.f};
    quad_mainloop(A2, LB, t, lane, acc);
#pragma unroll
    for (int ss = 0; ss < 4; ss++)
#pragma unroll
      for (int cf = 0; cf < 5; cf++)
#pragma unroll
        for (int r = 0; r < 4; r++) acc[ss][cf][r] = __expf(acc[ss][cf][r]);
    int cnt = bcnt[t];
    for (int n = 0; n < cnt; n++) {
      int b = bucket[t * 128 + n];
      float4 w[4];
#pragma unroll
      for (int ss = 0; ss < 4; ss++)
        w[ss] = *(const float4*)(wgt + b * 64 + ss * 16 + (lane >> 4) * 4);
#pragma unroll
      for (int cf = 0; cf < 5; cf++) {
        float local = 0.f;
#pragma unroll
        for (int ss = 0; ss < 4; ss++)
          local += w[ss].x * acc[ss][cf][0] + w[ss].y * acc[ss][cf][1] +
                   w[ss].z * acc[ss][cf][2] + w[ss].w * acc[ss][cf][3];
        local += __shfl_xor(local, 16, 64);
        local += __shfl_xor(local, 32, 64);
        int v = vbase + cf * 16 + (lane & 15);
        float contrib = bows[(size_t)b * VDIM + v] * __logf(local + EPSF);
        if (lane < 16) nacc += contrib;
      }
    }
  }
  nacc = wred64(nacc);
  __shared__ float p[4];
  if (lane == 0) p[wave] = nacc;
  __syncthreads();
  if (tid == 0) atomicAdd(&scal[0], p[0] + p[1] + p[2] + p[3]);
}

// ---------------- finalize ---------------------------------------------------
__global__ void k_finalize(const float* __restrict__ scal, float* __restrict__ out) {
  if (threadIdx.x == 0 && blockIdx.x == 0) {
    float nll = -scal[0];
    out[0] = nll + scal[1] + scal[2] + scal[3];
    out[1] = nll;
    out[2] = scal[1];
    out[3] = scal[2];
    out[4] = scal[3];
  }
}

extern "C" void kernel_launch(void* const* d_in, const int* in_sizes, int n_in,
                              void* d_out, int out_size, void* d_ws, size_t ws_size,
                              hipStream_t stream) {
  const float* bows  = (const float*)d_in[0];
  const float* nbows = (const float*)d_in[1];
  const float* rnn   = (const float*)d_in[2];
  const float* wemb  = (const float*)d_in[3];
  const float* mua   = (const float*)d_in[4];
  const float* lsa   = (const float*)d_in[5];
  const float* Wth   = (const float*)d_in[6];
  const float* bth   = (const float*)d_in[7];
  const float* Wmt   = (const float*)d_in[8];
  const float* bmt   = (const float*)d_in[9];
  const float* Wlt   = (const float*)d_in[10];
  const float* blt   = (const float*)d_in[11];
  const float* Wmap  = (const float*)d_in[12];
  const float* bmap  = (const float*)d_in[13];
  const float* Wih   = (const float*)d_in[14];
  const float* Whh   = (const float*)d_in[15];
  const float* bihp  = (const float*)d_in[16];
  const float* bhhp  = (const float*)d_in[17];
  const float* Wme   = (const float*)d_in[18];
  const float* bme   = (const float*)d_in[19];
  const float* Wle   = (const float*)d_in[20];
  const float* ble   = (const float*)d_in[21];
  const int* times   = (const int*)d_in[22];

  float* ws = (float*)d_ws;
  float* scal  = ws;                 // 8
  float* Z     = ws + 8;             // 2560
  float* hpre  = ws + 2568;          // 80000
  float* omap  = ws + 82568;         // 8000   (end of zeroed region: 90568 floats)
  float* xa    = ws + 90568;         // 8000
  float* xb    = ws + 98568;         // 8000
  float* lout  = ws + 106568;        // 8000
  float* Gin   = ws + 114568;        // 32000 (reused as MhLh after last k_rec)
  unsigned* WhhT = (unsigned*)(ws + 146568);   // 240000
  float* etas  = ws + 386568;        // 2000
  float* theta = ws + 388568;        // 5000
  float* wgt   = ws + 393568;        // 6400
  int* bcnt    = (int*)(ws + 399968);          // 64
  int* bucket  = (int*)(ws + 400032);          // 5120
  unsigned short* A2 = (unsigned short*)(ws + 405152);  // 819200 ushorts -> ends 814752
  unsigned short* B2 = (unsigned short*)(ws + 814752);  // 30080*320 ushorts = 19.25 MB

  float* mhlh = Gin;  // 40*128 floats, alias of Gin (dead after last k_rec)

  // fast path needs ws up to byte offset 814752*4 + 19251200 = 22510208
  bool fast = ws_size >= 23000000u;

  if (fast) {
    static bool attr_set = false;
    if (!attr_set) {
      auto kA = k_gemm<false>;
      auto kB = k_gemm<true>;
      (void)hipFuncSetAttribute((const void*)kA,
                                hipFuncAttributeMaxDynamicSharedMemorySize, GEMM_LDS);
      (void)hipFuncSetAttribute((const void*)kB,
                                hipFuncAttributeMaxDynamicSharedMemorySize, GEMM_LDS);
      attr_set = true;
    }
  }

  hipMemsetAsync(ws, 0, 90568 * sizeof(float), stream);

  k_prep_A2<<<3200, 256, 0, stream>>>(mua, A2);
  if (fast) k_prep_B<<<9400, 256, 0, stream>>>(wemb, B2);
  k_map2<<<dim3(313, 2), 256, 0, stream>>>(rnn, Wmap, bmap, omap);
  k_wt<<<300, 256, 0, stream>>>(Whh, WhhT);
  k_bucket<<<1, 128, 0, stream>>>(times, bcnt, bucket);

  if (fast)
    k_gemm<false><<<235, 512, GEMM_LDS, stream>>>(A2, B2, Z, nullptr, nullptr,
                                                  nullptr, nullptr, nullptr);
  else
    k_passA<<<NBLK_V, 256, 0, stream>>>(wemb, A2, Z);

  k_igemm<<<400, 256, 0, stream>>>(Wih, bihp, bhhp, omap, Gin, 0);
  k_rec<<<1, 1024, 0, stream>>>(WhhT, Gin, xa);
  k_igemm<<<400, 256, 0, stream>>>(Wih, bihp, bhhp, xa, Gin, 1);
  k_rec<<<1, 1024, 0, stream>>>(WhhT + 100 * 800, Gin, xb);
  k_igemm<<<400, 256, 0, stream>>>(Wih, bihp, bhhp, xb, Gin, 2);
  k_rec<<<1, 1024, 0, stream>>>(WhhT + 200 * 800, Gin, lout);

  k_eta_pre<<<40, 256, 0, stream>>>(Wme, bme, Wle, ble, lout, mhlh);
  k_eta_chain<<<1, 64, 0, stream>>>(Wme, Wle, mhlh, etas, scal);
  k_hpre<<<dim3(13, 47), 256, 0, stream>>>(nbows, Wth, hpre);
  k_theta<<<100, 256, 0, stream>>>(hpre, bth, Wth, Wmt, bmt, Wlt, blt, etas, times, theta, scal);
  k_wgt<<<25, 256, 0, stream>>>(theta, Z, times, wgt);
  k_klalpha<<<2344, 256, 0, stream>>>(mua, lsa, scal);

  if (fast)
    k_gemm<true><<<235, 512, GEMM_LDS, stream>>>(A2, B2, Z, wgt, bows, bcnt,
                                                 bucket, scal);
  else
    k_passB<<<NBLK_V, 256, 0, stream>>>(wemb, A2, wgt, bows, bcnt, bucket, scal);

  k_finalize<<<1, 64, 0, stream>>>(scal, (float*)d_out);
}

// Round 6
// 1126.741 us; speedup vs baseline: 1.8602x; 1.3994x over previous
//
#include <hip/hip_runtime.h>

#define KDIM 50
#define TDIM 40
#define VDIM 30000
#define THDIM 800
#define EHDIM 200
#define EDIM 300
#define BDIM 100
#define DELTAF 0.005f
#define EPSF 1e-6f
#define LOGD (-5.2983174f)
#define MROWS 2560   // TDIM*64 rows for MFMA A operand
#define KPAD 320     // E padded to 320
#define VROWS 30080  // V padded to 235*128
#define VT 80        // v-tile per MFMA block (fallback path)
#define NBLK_V 375   // 30000/80 (fallback path)
#define LBSTR 328    // fallback LDS B-tile row stride
#define GEMM_LDS 81920  // 128 rows * 320 cols * 2B

typedef __attribute__((ext_vector_type(8))) short bf16x8;
typedef __attribute__((ext_vector_type(4))) float f32x4;
typedef __attribute__((ext_vector_type(2))) _Float16 f16x2;
typedef unsigned int u32;

__device__ inline float wred64(float v) {
  v += __shfl_xor(v, 32, 64); v += __shfl_xor(v, 16, 64);
  v += __shfl_xor(v, 8, 64);  v += __shfl_xor(v, 4, 64);
  v += __shfl_xor(v, 2, 64);  v += __shfl_xor(v, 1, 64);
  return v;
}

__device__ inline unsigned short f2bf(float f) {
  union { float f; unsigned u; } x; x.f = f;
  unsigned r = x.u + 0x7fffu + ((x.u >> 16) & 1u);
  return (unsigned short)(r >> 16);
}

__device__ inline void gload_lds16(const void* g, void* l) {
  __builtin_amdgcn_global_load_lds(
      (const __attribute__((address_space(1))) u32*)g,
      (__attribute__((address_space(3))) u32*)l, 16, 0, 0);
}

// ---------------- A2 prep: mu_q_alpha[k][t][e] -> bf16 A2[t*64+k][e<320] ----
__global__ void k_prep_A2(const float* __restrict__ mu_q, unsigned short* __restrict__ A2) {
  int idx = blockIdx.x * 256 + threadIdx.x;   // 2560*320 = 819200
  if (idx >= MROWS * KPAD) return;
  int m = idx / KPAD, e = idx % KPAD;
  int t = m >> 6, kp = m & 63;
  float v = 0.f;
  if (kp < KDIM && e < EDIM) v = mu_q[(kp * TDIM + t) * EDIM + e];
  A2[idx] = f2bf(v);
}

// ---------------- B2 prep: word_emb fp32 [30000][300] -> bf16 [30080][320] --
// PRE-SWIZZLED: 16B slot s (e>>3) stored at physical slot s ^ (v&7), so the
// GEMM's linear global_load_lds staging + XOR'd ds_read_b128 is bank-balanced.
__global__ void k_prep_B(const float* __restrict__ we, unsigned short* __restrict__ B2) {
  int idx = blockIdx.x * 256 + threadIdx.x;   // 30080*80 = 2406400
  if (idx >= VROWS * 80) return;
  int v = idx / 80, e4 = (idx % 80) * 4;
  ushort4 o = {0, 0, 0, 0};
  if (v < VDIM && e4 < EDIM) {
    float4 w = *(const float4*)(we + (size_t)v * EDIM + e4);
    o.x = f2bf(w.x); o.y = f2bf(w.y); o.z = f2bf(w.z); o.w = f2bf(w.w);
  }
  int dcol = (((e4 >> 3) ^ (v & 7)) << 3) | (e4 & 7);
  *(ushort4*)(B2 + (size_t)v * KPAD + dcol) = o;
}

// ---------------- out_map = rnn_inp @ W_map^T + b_map  [40,200] -------------
#define MP_VS 96
#define RS_STR 44
#define WS_STR 104
__global__ __launch_bounds__(256) void k_map2(const float* __restrict__ rnn,
                                              const float* __restrict__ Wmap,
                                              const float* __restrict__ bmap,
                                              float* __restrict__ omap) {
  __shared__ __align__(16) float rs[MP_VS * RS_STR];
  __shared__ __align__(16) float wsb[MP_VS * WS_STR];
  int c = blockIdx.x, eh = blockIdx.y;
  int v0 = c * MP_VS, e0 = eh * 100;
  int tid = threadIdx.x;
  for (int idx = tid; idx < TDIM * MP_VS; idx += 256) {
    int t = idx / MP_VS, vv = idx % MP_VS;
    int v = v0 + vv;
    rs[vv * RS_STR + t] = (v < VDIM) ? rnn[(size_t)t * VDIM + v] : 0.f;
  }
  for (int idx = tid; idx < 100 * MP_VS; idx += 256) {
    int e = idx / MP_VS, vv = idx % MP_VS;
    int v = v0 + vv;
    wsb[vv * WS_STR + e] = (v < VDIM) ? Wmap[(size_t)(e0 + e) * VDIM + v] : 0.f;
  }
  __syncthreads();
  if (tid >= 250) return;
  int eg = tid / 10, tg = tid % 10;
  float acc[4][4];
#pragma unroll
  for (int i = 0; i < 4; i++)
#pragma unroll
    for (int j = 0; j < 4; j++) acc[i][j] = 0.f;
  int nvv = min(MP_VS, VDIM - v0);
  for (int vv = 0; vv < nvv; vv++) {
    float4 wv = *(const float4*)&wsb[vv * WS_STR + eg * 4];
    float4 rv = *(const float4*)&rs[vv * RS_STR + tg * 4];
    float wa[4] = {wv.x, wv.y, wv.z, wv.w};
    float ra[4] = {rv.x, rv.y, rv.z, rv.w};
#pragma unroll
    for (int i = 0; i < 4; i++)
#pragma unroll
      for (int j = 0; j < 4; j++) acc[i][j] += wa[i] * ra[j];
  }
#pragma unroll
  for (int i = 0; i < 4; i++) {
    int e = e0 + eg * 4 + i;
#pragma unroll
    for (int j = 0; j < 4; j++) {
      int t = tg * 4 + j;
      float a = acc[i][j];
      if (c == 0) a += bmap[e];
      atomicAdd(&omap[t * EHDIM + e], a);
    }
  }
}

// ---------------- Whh transpose+pack to f16 pairs: WhhT[l][jp][i] -----------
// f16 (11-bit mantissa) instead of bf16: weights |w|<~0.3, strictly more
// precise than the bf16 version; consumed by k_rec's v_dot2_f32_f16.
__global__ void k_wt(const float* __restrict__ Whh, unsigned* __restrict__ WhhT) {
  int l = blockIdx.x / 100, jp = blockIdx.x % 100;
  for (int i = threadIdx.x; i < THDIM; i += 256) {
    float w0 = Whh[(l * THDIM + i) * EHDIM + 2 * jp];
    float w1 = Whh[(l * THDIM + i) * EHDIM + 2 * jp + 1];
    _Float16 a = (_Float16)w0, b = (_Float16)w1;
    unsigned short ua, ub;
    __builtin_memcpy(&ua, &a, 2);
    __builtin_memcpy(&ub, &b, 2);
    WhhT[(l * 100 + jp) * THDIM + i] = (unsigned)ua | ((unsigned)ub << 16);
  }
}

// ---------------- LSTM input GEMM: G[t][i] = Wih[l][i]·x[t] + bih + bhh -----
__global__ void k_igemm(const float* __restrict__ Wih, const float* __restrict__ bih,
                        const float* __restrict__ bhh, const float* __restrict__ x,
                        float* __restrict__ G, int l) {
  int wave = threadIdx.x >> 6, lane = threadIdx.x & 63;
  int d0 = blockIdx.x * 80 + wave * 20;
  for (int n = 0; n < 20; n++) {
    int d = d0 + n;
    int t = d / THDIM, i = d % THDIM;
    const float* row = Wih + (l * THDIM + i) * EHDIM;
    const float* xt = x + t * EHDIM;
    float acc = 0.f;
#pragma unroll
    for (int m = 0; m < 4; m++) { int j = m * 64 + lane; if (j < EHDIM) acc += row[j] * xt[j]; }
    acc = wred64(acc);
    if (lane == 0) G[t * THDIM + i] = acc + bih[l * THDIM + i] + bhh[l * THDIM + i];
  }
}

// ---------------- LSTM recurrence (1 block; weight row in REGISTERS) --------
// v2: thread i holds its full 200-wide recurrent weight row as 100 packed-f16
// pairs in VGPRs (loaded once). Per step: 25 broadcast ds_read_b128 of packed
// h + 100 v_dot2_f32_f16 (2 accs). Old version re-streamed 320KB/step from L2
// with a 1-deep load pipe (VGPR=24) -> 5.2us/step latency-bound.
__global__ __launch_bounds__(1024) void k_rec(const unsigned* __restrict__ WT,
                                              const float* __restrict__ G,
                                              float* __restrict__ xout) {
  __shared__ __align__(16) unsigned short h16[EHDIM];  // packed f16 h
  __shared__ float g[THDIM];
  int tid = threadIdx.x;
  unsigned wreg[100];
  if (tid < THDIM) {
    const unsigned* wp = WT + tid;
#pragma unroll
    for (int q = 0; q < 100; q++) wreg[q] = wp[q * THDIM];
  }
  if (tid < EHDIM) h16[tid] = 0;
  float c = 0.f;
  __syncthreads();
  for (int t = 0; t < TDIM; t++) {
    if (tid < THDIM) {
      float a0 = G[t * THDIM + tid], a1 = 0.f;
      const uint4* hp = (const uint4*)h16;   // 4 f16-pairs per uint4
#pragma unroll
      for (int q4 = 0; q4 < 25; q4++) {
        uint4 hh = hp[q4];
        union { unsigned u; f16x2 h; } x0, x1, x2, x3, w0, w1, w2, w3;
        x0.u = hh.x; x1.u = hh.y; x2.u = hh.z; x3.u = hh.w;
        w0.u = wreg[q4 * 4 + 0]; w1.u = wreg[q4 * 4 + 1];
        w2.u = wreg[q4 * 4 + 2]; w3.u = wreg[q4 * 4 + 3];
        a0 = __builtin_amdgcn_fdot2(w0.h, x0.h, a0, false);
        a1 = __builtin_amdgcn_fdot2(w1.h, x1.h, a1, false);
        a0 = __builtin_amdgcn_fdot2(w2.h, x2.h, a0, false);
        a1 = __builtin_amdgcn_fdot2(w3.h, x3.h, a1, false);
      }
      g[tid] = a0 + a1;
    }
    __syncthreads();
    if (tid < EHDIM) {
      float si = 1.f / (1.f + __expf(-g[tid]));
      float sf = 1.f / (1.f + __expf(-g[200 + tid]));
      float sg = tanhf(g[400 + tid]);
      float so = 1.f / (1.f + __expf(-g[600 + tid]));
      c = sf * c + si * sg;
      float hn = so * tanhf(c);
      xout[t * EHDIM + tid] = hn;
      _Float16 hf = (_Float16)hn;
      unsigned short hu;
      __builtin_memcpy(&hu, &hf, 2);
      h16[tid] = hu;
    }
    __syncthreads();
  }
}

// ---------------- eta: parallel part  MhLh[t][j] = W[:, :200]·h_t + b -------
// j<50: mu row j (Wme,bme); j in 50..99: ls row j-50 (Wle,ble). 40 blocks.
__global__ void k_eta_pre(const float* __restrict__ Wmu, const float* __restrict__ bmu,
                          const float* __restrict__ Wls, const float* __restrict__ bls,
                          const float* __restrict__ lout, float* __restrict__ MhLh) {
  int t = blockIdx.x;
  int wave = threadIdx.x >> 6, lane = threadIdx.x & 63;
  const float* xt = lout + t * EHDIM;
  for (int jb = wave; jb < 2 * KDIM; jb += 4) {
    const float* row = (jb < KDIM) ? (Wmu + jb * 250) : (Wls + (jb - KDIM) * 250);
    float acc = 0.f;
#pragma unroll
    for (int m = 0; m < 4; m++) {
      int j = m * 64 + lane;
      if (j < EHDIM) acc += row[j] * xt[j];
    }
    acc = wred64(acc);
    if (lane == 0) {
      float b = (jb < KDIM) ? bmu[jb] : bls[jb - KDIM];
      MhLh[t * 128 + jb] = acc + b;
    }
  }
}

// ---------------- eta: sequential chain (1 wave, weights in registers) ------
__global__ void k_eta_chain(const float* __restrict__ Wmu, const float* __restrict__ Wls,
                            const float* __restrict__ MhLh, float* __restrict__ etas,
                            float* __restrict__ scal) {
  __shared__ float eta[64];
  int j = threadIdx.x;  // 64 = one wave
  float wm[KDIM], wl[KDIM];
  if (j < KDIM) {
#pragma unroll
    for (int k = 0; k < KDIM; k++) {
      wm[k] = Wmu[j * 250 + EHDIM + k];
      wl[k] = Wls[j * 250 + EHDIM + k];
    }
  } else {
#pragma unroll
    for (int k = 0; k < KDIM; k++) { wm[k] = 0.f; wl[k] = 0.f; }
  }
  eta[j] = 0.f;
  float ep = 0.f;   // eta_{t-1}[j]
  float kl = 0.f;
  __syncthreads();
  for (int t = 0; t < TDIM; t++) {
    float am = 0.f, al = 0.f;
#pragma unroll
    for (int k = 0; k < KDIM; k++) {
      float e = eta[k];          // broadcast read
      am += wm[k] * e;
      al += wl[k] * e;
    }
    float v = 0.f, mu = 0.f;
    if (j < KDIM) {
      mu = MhLh[t * 128 + j] + am;
      float ls = MhLh[t * 128 + KDIM + j] + al;
      float d = mu - ep;
      if (t == 0) v = 0.5f * ((__expf(ls) + mu * mu) / (1.f + EPSF) - 1.f - ls);
      else        v = 0.5f * ((__expf(ls) + d * d) / (DELTAF + EPSF) - 1.f + LOGD - ls);
      etas[t * KDIM + j] = mu;
    }
    v = wred64(v);
    if (j == 0) kl += v;
    __syncthreads();
    if (j < KDIM) { eta[j] = mu; ep = mu; }
    __syncthreads();
  }
  if (j == 0) scal[2] = kl;
}

// ---------------- h_pre = nb @ W_theta[:, :V]^T  (MFMA, bf16 hi+lo split) ---
#define HPM_STR 40
__global__ __launch_bounds__(256, 2) void k_hpre(const float* __restrict__ nb,
                                                 const float* __restrict__ Wth,
                                                 float* __restrict__ h_pre) {
  __shared__ __align__(16) unsigned short Ahi[64 * HPM_STR];
  __shared__ __align__(16) unsigned short Alo[64 * HPM_STR];
  __shared__ __align__(16) unsigned short Bhi[112 * HPM_STR];
  __shared__ __align__(16) unsigned short Blo[112 * HPM_STR];
  int tid = threadIdx.x, wv = tid >> 6, lane = tid & 63;
  int r15 = lane & 15, gh = lane >> 4;
  int mt = blockIdx.x;                        // 13 m-tiles of 64 TH rows
  int s0 = blockIdx.y * 20;
  int s1 = min(s0 + 20, 938);                 // 938 K-steps of 32 cover 30016
  f32x4 acc[7];
#pragma unroll
  for (int j = 0; j < 7; ++j) acc[j] = (f32x4){0.f, 0.f, 0.f, 0.f};
  int srow = tid >> 3, sk4 = (tid & 7) * 4;   // float col within 32-k tile
  for (int s = s0; s < s1; ++s) {
    int k = s * 32 + sk4;
    bool kok = (k + 3) < VDIM;                // 30000%4==0: never straddles
    float4 av[2], bv[4];
#pragma unroll
    for (int it = 0; it < 2; ++it) {
      int th = mt * 64 + srow + it * 32;
      float4 v = {0.f, 0.f, 0.f, 0.f};
      if (th < THDIM && kok) {
        const float* p = Wth + (size_t)th * 30050 + k;  // 8B-aligned only
        float2 p0 = *(const float2*)p;
        float2 p1 = *(const float2*)(p + 2);
        v.x = p0.x; v.y = p0.y; v.z = p1.x; v.w = p1.y;
      }
      av[it] = v;
    }
#pragma unroll
    for (int it = 0; it < 4; ++it) {
      int b = srow + it * 32;
      float4 v = {0.f, 0.f, 0.f, 0.f};
      if (b < BDIM && kok) v = *(const float4*)(nb + (size_t)b * VDIM + k);
      bv[it] = v;
    }
    __syncthreads();   // all waves done reading LDS from previous step
#pragma unroll
    for (int it = 0; it < 2; ++it) {
      int row = srow + it * 32;
      float fa[4] = {av[it].x, av[it].y, av[it].z, av[it].w};
      unsigned short hh[4], ll[4];
#pragma unroll
      for (int u = 0; u < 4; ++u) {
        unsigned short hv = f2bf(fa[u]);
        union { unsigned uu; float f; } uf; uf.uu = (unsigned)hv << 16;
        hh[u] = hv; ll[u] = f2bf(fa[u] - uf.f);
      }
      *(ushort4*)(Ahi + row * HPM_STR + sk4) = (ushort4){hh[0], hh[1], hh[2], hh[3]};
      *(ushort4*)(Alo + row * HPM_STR + sk4) = (ushort4){ll[0], ll[1], ll[2], ll[3]};
    }
#pragma unroll
    for (int it = 0; it < 4; ++it) {
      int row = srow + it * 32;
      if (row < 112) {
        float fb[4] = {bv[it].x, bv[it].y, bv[it].z, bv[it].w};
        unsigned short hh[4], ll[4];
#pragma unroll
        for (int u = 0; u < 4; ++u) {
          unsigned short hv = f2bf(fb[u]);
          union { unsigned uu; float f; } uf; uf.uu = (unsigned)hv << 16;
          hh[u] = hv; ll[u] = f2bf(fb[u] - uf.f);
        }
        *(ushort4*)(Bhi + row * HPM_STR + sk4) = (ushort4){hh[0], hh[1], hh[2], hh[3]};
        *(ushort4*)(Blo + row * HPM_STR + sk4) = (ushort4){ll[0], ll[1], ll[2], ll[3]};
      }
    }
    __syncthreads();
    bf16x8 ah = *(const bf16x8*)(Ahi + (wv * 16 + r15) * HPM_STR + gh * 8);
    bf16x8 al = *(const bf16x8*)(Alo + (wv * 16 + r15) * HPM_STR + gh * 8);
#pragma unroll
    for (int sj = 0; sj < 7; ++sj) {
      bf16x8 bh = *(const bf16x8*)(Bhi + (sj * 16 + r15) * HPM_STR + gh * 8);
      bf16x8 bl = *(const bf16x8*)(Blo + (sj * 16 + r15) * HPM_STR + gh * 8);
      acc[sj] = __builtin_amdgcn_mfma_f32_16x16x32_bf16(ah, bh, acc[sj], 0, 0, 0);
      acc[sj] = __builtin_amdgcn_mfma_f32_16x16x32_bf16(ah, bl, acc[sj], 0, 0, 0);
      acc[sj] = __builtin_amdgcn_mfma_f32_16x16x32_bf16(al, bh, acc[sj], 0, 0, 0);
    }
  }
#pragma unroll
  for (int sj = 0; sj < 7; ++sj) {
    int b = sj * 16 + r15;
    if (b >= BDIM) continue;
#pragma unroll
    for (int r = 0; r < 4; ++r) {
      int th = mt * 64 + wv * 16 + gh * 4 + r;
      if (th < THDIM) atomicAdd(&h_pre[b * THDIM + th], acc[sj][r]);
    }
  }
}

// ---------------- theta path: tanh, softmax, kl_theta -----------------------
__global__ void k_theta(const float* __restrict__ hpre, const float* __restrict__ bth,
                        const float* __restrict__ Wth, const float* __restrict__ Wmt,
                        const float* __restrict__ bmt, const float* __restrict__ Wlt,
                        const float* __restrict__ blt, const float* __restrict__ etas,
                        const int* __restrict__ times, float* __restrict__ theta,
                        float* __restrict__ scal) {
  __shared__ float et[KDIM];
  __shared__ float hl[THDIM];
  __shared__ float mu_s[KDIM], ls_s[KDIM];
  int b = blockIdx.x, tid = threadIdx.x;
  if (tid < KDIM) et[tid] = etas[times[b] * KDIM + tid];
  __syncthreads();
  for (int th = tid; th < THDIM; th += 256) {
    float acc = hpre[b * THDIM + th] + bth[th];
    const float* wrow = Wth + (size_t)th * 30050 + VDIM;
#pragma unroll 10
    for (int k = 0; k < KDIM; k++) acc += et[k] * wrow[k];
    hl[th] = tanhf(acc);
  }
  __syncthreads();
  int wave = tid >> 6, lane = tid & 63;
  for (int jb = wave; jb < 2 * KDIM; jb += 4) {
    const float* row = (jb < KDIM) ? (Wmt + jb * THDIM) : (Wlt + (jb - KDIM) * THDIM);
    float acc = 0.f;
#pragma unroll
    for (int m = 0; m < 13; m++) { int j = m * 64 + lane; if (j < THDIM) acc += row[j] * hl[j]; }
    acc = wred64(acc);
    if (lane == 0) {
      if (jb < KDIM) mu_s[jb] = acc + bmt[jb];
      else ls_s[jb - KDIM] = acc + blt[jb - KDIM];
    }
  }
  __syncthreads();
  if (tid < 64) {
    float m = (tid < KDIM) ? mu_s[tid] : -1e30f;
    float mx = m;
#pragma unroll
    for (int o = 32; o >= 1; o >>= 1) mx = fmaxf(mx, __shfl_xor(mx, o, 64));
    float e = (tid < KDIM) ? __expf(m - mx) : 0.f;
    float s = wred64(e);
    if (tid < KDIM) theta[b * KDIM + tid] = e / s;
    float v = 0.f;
    if (tid < KDIM) {
      float ls = ls_s[tid];
      float d = mu_s[tid] - et[tid];
      v = 0.5f * ((__expf(ls) + d * d) / (1.f + EPSF) - 1.f - ls);
    }
    v = wred64(v);
    if (tid == 0) atomicAdd(&scal[3], v);
  }
}

// ---------------- kl_alpha ---------------------------------------------------
__global__ void k_klalpha(const float* __restrict__ mu, const float* __restrict__ ls,
                          float* __restrict__ scal) {
  int idx = blockIdx.x * 256 + threadIdx.x;
  float v = 0.f;
  if (idx < KDIM * TDIM * EDIM) {
    int t = (idx / EDIM) % TDIM;
    float l = ls[idx], m = mu[idx];
    if (t == 0) v = 0.5f * ((__expf(l) + m * m) / (1.f + EPSF) - 1.f - l);
    else { float d = m - mu[idx - EDIM]; v = 0.5f * ((__expf(l) + d * d) / (DELTAF + EPSF) - 1.f + LOGD - l); }
  }
  v = wred64(v);
  __shared__ float p[4];
  if ((threadIdx.x & 63) == 0) p[threadIdx.x >> 6] = v;
  __syncthreads();
  if (threadIdx.x == 0) atomicAdd(&scal[1], p[0] + p[1] + p[2] + p[3]);
}

// ---------------- time buckets ----------------------------------------------
__global__ void k_bucket(const int* __restrict__ times, int* __restrict__ bcnt,
                         int* __restrict__ bucket) {
  __shared__ int cnt[TDIM];
  int tid = threadIdx.x;  // 128
  if (tid < TDIM) cnt[tid] = 0;
  __syncthreads();
  if (tid < BDIM) {
    int t = times[tid];
    int s = atomicAdd(&cnt[t], 1);
    bucket[t * 128 + s] = tid;
  }
  __syncthreads();
  if (tid < TDIM) bcnt[tid] = cnt[tid];
}

// ---------------- wgt[b][k] = theta[b][k] / Z[t_b*64+k] ---------------------
__global__ void k_wgt(const float* __restrict__ theta, const float* __restrict__ Z,
                      const int* __restrict__ times, float* __restrict__ wgt) {
  int idx = blockIdx.x * 256 + threadIdx.x;  // 6400
  if (idx >= BDIM * 64) return;
  int b = idx >> 6, k = idx & 63;
  float v = 0.f;
  if (k < KDIM) v = theta[b * KDIM + k] / Z[times[b] * 64 + k];
  wgt[idx] = v;
}

// ================= B-stationary MFMA GEMM (both passes) =====================
template <bool PASSB>
__global__ __launch_bounds__(512, 2) void k_gemm(
    const unsigned short* __restrict__ A2, const unsigned short* __restrict__ B2,
    float* __restrict__ Z, const float* __restrict__ wgt,
    const float* __restrict__ bows, const int* __restrict__ bcnt,
    const int* __restrict__ bucket, float* __restrict__ scal) {
  extern __shared__ __align__(16) unsigned short Bs[];  // [128][320] swizzled
  __shared__ float p[8];
  int tid = threadIdx.x, wv = tid >> 6, lane = tid & 63;
  int vbase = blockIdx.x * 128;
  int r15 = lane & 15, gh = lane >> 4, x7 = r15 & 7;

  // ---- stage 80 KB linearly: 80 chunks of 1 KB, 10 per wave
  const unsigned short* gB = B2 + (size_t)vbase * KPAD;
#pragma unroll
  for (int c = 0; c < 10; ++c) {
    int chunk = wv * 10 + c;
    gload_lds16(gB + chunk * 512 + lane * 8, Bs + chunk * 512);
  }
  __syncthreads();

  const unsigned short* Br = Bs + r15 * KPAD;
  float nacc = 0.f;

  for (int jj = 0; jj < 5; ++jj) {
    int q = jj * 8 + wv;  // t-quad owned by this wave this round
    f32x4 acc[4][8];
#pragma unroll
    for (int si = 0; si < 4; ++si)
#pragma unroll
      for (int sj = 0; sj < 8; ++sj) acc[si][sj] = (f32x4){0.f, 0.f, 0.f, 0.f};

    const bf16x8* ab = (const bf16x8*)(A2 + (size_t)(q * 64 + r15) * KPAD) + gh;
#pragma unroll 2
    for (int kk = 0; kk < 10; ++kk) {
      bf16x8 a0 = ab[kk * 4];
      bf16x8 a1 = ab[640 + kk * 4];
      bf16x8 a2 = ab[1280 + kk * 4];
      bf16x8 a3 = ab[1920 + kk * 4];
      int spo = (((kk * 4 + gh) ^ x7) << 3);
#pragma unroll
      for (int sj = 0; sj < 8; ++sj) {
        bf16x8 b = *(const bf16x8*)(Br + sj * 5120 + spo);
        acc[0][sj] = __builtin_amdgcn_mfma_f32_16x16x32_bf16(a0, b, acc[0][sj], 0, 0, 0);
        acc[1][sj] = __builtin_amdgcn_mfma_f32_16x16x32_bf16(a1, b, acc[1][sj], 0, 0, 0);
        acc[2][sj] = __builtin_amdgcn_mfma_f32_16x16x32_bf16(a2, b, acc[2][sj], 0, 0, 0);
        acc[3][sj] = __builtin_amdgcn_mfma_f32_16x16x32_bf16(a3, b, acc[3][sj], 0, 0, 0);
      }
    }

    if (!PASSB) {
      // Z[m] += sum_v exp(logit)
#pragma unroll
      for (int si = 0; si < 4; ++si) {
#pragma unroll
        for (int r = 0; r < 4; ++r) {
          float es = 0.f;
#pragma unroll
          for (int sj = 0; sj < 8; ++sj) {
            int v = vbase + sj * 16 + r15;
            es += (v < VDIM) ? __expf(acc[si][sj][r]) : 0.f;
          }
          es += __shfl_xor(es, 1, 64); es += __shfl_xor(es, 2, 64);
          es += __shfl_xor(es, 4, 64); es += __shfl_xor(es, 8, 64);
          if (r15 == 0) atomicAdd(&Z[q * 64 + si * 16 + gh * 4 + r], es);
        }
      }
    } else {
#pragma unroll
      for (int si = 0; si < 4; ++si)
#pragma unroll
        for (int sj = 0; sj < 8; ++sj)
#pragma unroll
          for (int r = 0; r < 4; ++r) acc[si][sj][r] = __expf(acc[si][sj][r]);
      int cnt = bcnt[q];
      for (int n = 0; n < cnt; ++n) {
        int b = bucket[q * 128 + n];
        float4 w4[4];
#pragma unroll
        for (int si = 0; si < 4; ++si)
          w4[si] = *(const float4*)(wgt + b * 64 + si * 16 + gh * 4);
#pragma unroll
        for (int sj = 0; sj < 8; ++sj) {
          float local = 0.f;
#pragma unroll
          for (int si = 0; si < 4; ++si)
            local += w4[si].x * acc[si][sj][0] + w4[si].y * acc[si][sj][1] +
                     w4[si].z * acc[si][sj][2] + w4[si].w * acc[si][sj][3];
          local += __shfl_xor(local, 16, 64);
          local += __shfl_xor(local, 32, 64);
          int v = vbase + sj * 16 + r15;
          if (lane < 16 && v < VDIM)
            nacc += bows[(size_t)b * VDIM + v] * __logf(local + EPSF);
        }
      }
    }
  }

  if (PASSB) {
    nacc = wred64(nacc);
    if (lane == 0) p[wv] = nacc;
    __syncthreads();
    if (tid == 0)
      atomicAdd(&scal[0], p[0] + p[1] + p[2] + p[3] + p[4] + p[5] + p[6] + p[7]);
  }
}

// ================= fallback-path MFMA kernels (round-1, known-good) =========
__device__ inline void stage_B(const float* __restrict__ we, int vbase,
                               unsigned short* LB, int tid) {
  for (int q = tid; q < VT * 75; q += 256) {
    int vp = q / 75, e4 = (q % 75) * 4;
    float4 w = *(const float4*)(we + (size_t)(vbase + vp) * EDIM + e4);
    unsigned* p32 = (unsigned*)(LB + vp * LBSTR + e4);
    p32[0] = (unsigned)f2bf(w.x) | ((unsigned)f2bf(w.y) << 16);
    p32[1] = (unsigned)f2bf(w.z) | ((unsigned)f2bf(w.w) << 16);
  }
  for (int q = tid; q < VT * 28; q += 256) {
    int vp = q / 28, e = 300 + q % 28;
    LB[vp * LBSTR + e] = 0;
  }
}

__device__ inline void quad_mainloop(const unsigned short* __restrict__ A2,
                                     const unsigned short* LB, int quad, int lane,
                                     f32x4 (&acc)[4][5]) {
  int mrow = quad * 64 + (lane & 15);
  int eoff = (lane >> 4) * 8;
  const bf16x8* ap[4];
#pragma unroll
  for (int ss = 0; ss < 4; ss++)
    ap[ss] = (const bf16x8*)(A2 + (size_t)(mrow + ss * 16) * KPAD + eoff);
  const unsigned short* bp = LB + (lane & 15) * LBSTR + eoff;
#pragma unroll
  for (int kk = 0; kk < 10; kk++) {
    bf16x8 a[4];
#pragma unroll
    for (int ss = 0; ss < 4; ss++) a[ss] = ap[ss][kk * 4];
#pragma unroll
    for (int cf = 0; cf < 5; cf++) {
      bf16x8 b = *(const bf16x8*)(bp + cf * 16 * LBSTR + kk * 32);
#pragma unroll
      for (int ss = 0; ss < 4; ss++)
        acc[ss][cf] = __builtin_amdgcn_mfma_f32_16x16x32_bf16(a[ss], b, acc[ss][cf], 0, 0, 0);
    }
  }
}

__global__ __launch_bounds__(256, 2) void k_passA(const float* __restrict__ we,
                                                  const unsigned short* __restrict__ A2,
                                                  float* __restrict__ Z) {
  __shared__ __align__(16) unsigned short LB[VT * LBSTR];
  int tid = threadIdx.x, vbase = blockIdx.x * VT;
  stage_B(we, vbase, LB, tid);
  __syncthreads();
  int wave = tid >> 6, lane = tid & 63;
  for (int q = wave; q < TDIM; q += 4) {
    f32x4 acc[4][5];
#pragma unroll
    for (int ss = 0; ss < 4; ss++)
#pragma unroll
      for (int cf = 0; cf < 5; cf++) acc[ss][cf] = (f32x4){0.f, 0.f, 0.f, 0.f};
    quad_mainloop(A2, LB, q, lane, acc);
#pragma unroll
    for (int ss = 0; ss < 4; ss++) {
#pragma unroll
      for (int r = 0; r < 4; r++) {
        float s = __expf(acc[ss][0][r]) + __expf(acc[ss][1][r]) + __expf(acc[ss][2][r]) +
                  __expf(acc[ss][3][r]) + __expf(acc[ss][4][r]);
        s += __shfl_xor(s, 1, 64); s += __shfl_xor(s, 2, 64);
        s += __shfl_xor(s, 4, 64); s += __shfl_xor(s, 8, 64);
        if ((lane & 15) == 0)
          atomicAdd(&Z[q * 64 + ss * 16 + (lane >> 4) * 4 + r], s);
      }
    }
  }
}

__global__ __launch_bounds__(256, 2) void k_passB(const float* __restrict__ we,
                                                  const unsigned short* __restrict__ A2,
                                                  const float* __restrict__ wgt,
                                                  const float* __restrict__ bows,
                                                  const int* __restrict__ bcnt,
                                                  const int* __restrict__ bucket,
                                                  float* __restrict__ scal) {
  __shared__ __align__(16) unsigned short LB[VT * LBSTR];
  int tid = threadIdx.x, vbase = blockIdx.x * VT;
  stage_B(we, vbase, LB, tid);
  __syncthreads();
  int wave = tid >> 6, lane = tid & 63;
  float nacc = 0.f;
  for (int t = wave; t < TDIM; t += 4) {
    f32x4 acc[4][5];
#pragma unroll
    for (int ss = 0; ss < 4; ss++)
#pragma unroll
      for (int cf = 0; cf < 5; cf++) acc[ss][cf] = (f32x4){0.f, 0.f, 0.f, 0.f};
    quad_mainloop(A2, LB, t, lane, acc);
#pragma unroll
    for (int ss = 0; ss < 4; ss++)
#pragma unroll
      for (int cf = 0; cf < 5; cf++)
#pragma unroll
        for (int r = 0; r < 4; r++) acc[ss][cf][r] = __expf(acc[ss][cf][r]);
    int cnt = bcnt[t];
    for (int n = 0; n < cnt; n++) {
      int b = bucket[t * 128 + n];
      float4 w[4];
#pragma unroll
      for (int ss = 0; ss < 4; ss++)
        w[ss] = *(const float4*)(wgt + b * 64 + ss * 16 + (lane >> 4) * 4);
#pragma unroll
      for (int cf = 0; cf < 5; cf++) {
        float local = 0.f;
#pragma unroll
        for (int ss = 0; ss < 4; ss++)
          local += w[ss].x * acc[ss][cf][0] + w[ss].y * acc[ss][cf][1] +
                   w[ss].z * acc[ss][cf][2] + w[ss].w * acc[ss][cf][3];
        local += __shfl_xor(local, 16, 64);
        local += __shfl_xor(local, 32, 64);
        int v = vbase + cf * 16 + (lane & 15);
        float contrib = bows[(size_t)b * VDIM + v] * __logf(local + EPSF);
        if (lane < 16) nacc += contrib;
      }
    }
  }
  nacc = wred64(nacc);
  __shared__ float p[4];
  if (lane == 0) p[wave] = nacc;
  __syncthreads();
  if (tid == 0) atomicAdd(&scal[0], p[0] + p[1] + p[2] + p[3]);
}

// ---------------- finalize ---------------------------------------------------
__global__ void k_finalize(const float* __restrict__ scal, float* __restrict__ out) {
  if (threadIdx.x == 0 && blockIdx.x == 0) {
    float nll = -scal[0];
    out[0] = nll + scal[1] + scal[2] + scal[3];
    out[1] = nll;
    out[2] = scal[1];
    out[3] = scal[2];
    out[4] = scal[3];
  }
}

extern "C" void kernel_launch(void* const* d_in, const int* in_sizes, int n_in,
                              void* d_out, int out_size, void* d_ws, size_t ws_size,
                              hipStream_t stream) {
  const float* bows  = (const float*)d_in[0];
  const float* nbows = (const float*)d_in[1];
  const float* rnn   = (const float*)d_in[2];
  const float* wemb  = (const float*)d_in[3];
  const float* mua   = (const float*)d_in[4];
  const float* lsa   = (const float*)d_in[5];
  const float* Wth   = (const float*)d_in[6];
  const float* bth   = (const float*)d_in[7];
  const float* Wmt   = (const float*)d_in[8];
  const float* bmt   = (const float*)d_in[9];
  const float* Wlt   = (const float*)d_in[10];
  const float* blt   = (const float*)d_in[11];
  const float* Wmap  = (const float*)d_in[12];
  const float* bmap  = (const float*)d_in[13];
  const float* Wih   = (const float*)d_in[14];
  const float* Whh   = (const float*)d_in[15];
  const float* bihp  = (const float*)d_in[16];
  const float* bhhp  = (const float*)d_in[17];
  const float* Wme   = (const float*)d_in[18];
  const float* bme   = (const float*)d_in[19];
  const float* Wle   = (const float*)d_in[20];
  const float* ble   = (const float*)d_in[21];
  const int* times   = (const int*)d_in[22];

  float* ws = (float*)d_ws;
  float* scal  = ws;                 // 8
  float* Z     = ws + 8;             // 2560
  float* hpre  = ws + 2568;          // 80000
  float* omap  = ws + 82568;         // 8000   (end of zeroed region: 90568 floats)
  float* xa    = ws + 90568;         // 8000
  float* xb    = ws + 98568;         // 8000
  float* lout  = ws + 106568;        // 8000
  float* Gin   = ws + 114568;        // 32000 (reused as MhLh after last k_rec)
  unsigned* WhhT = (unsigned*)(ws + 146568);   // 240000
  float* etas  = ws + 386568;        // 2000
  float* theta = ws + 388568;        // 5000
  float* wgt   = ws + 393568;        // 6400
  int* bcnt    = (int*)(ws + 399968);          // 64
  int* bucket  = (int*)(ws + 400032);          // 5120
  unsigned short* A2 = (unsigned short*)(ws + 405152);  // 819200 ushorts -> ends 814752
  unsigned short* B2 = (unsigned short*)(ws + 814752);  // 30080*320 ushorts = 19.25 MB

  float* mhlh = Gin;  // 40*128 floats, alias of Gin (dead after last k_rec)

  // fast path needs ws up to byte offset 814752*4 + 19251200 = 22510208
  bool fast = ws_size >= 23000000u;

  if (fast) {
    static bool attr_set = false;
    if (!attr_set) {
      auto kA = k_gemm<false>;
      auto kB = k_gemm<true>;
      (void)hipFuncSetAttribute((const void*)kA,
                                hipFuncAttributeMaxDynamicSharedMemorySize, GEMM_LDS);
      (void)hipFuncSetAttribute((const void*)kB,
                                hipFuncAttributeMaxDynamicSharedMemorySize, GEMM_LDS);
      attr_set = true;
    }
  }

  hipMemsetAsync(ws, 0, 90568 * sizeof(float), stream);

  k_prep_A2<<<3200, 256, 0, stream>>>(mua, A2);
  if (fast) k_prep_B<<<9400, 256, 0, stream>>>(wemb, B2);
  k_map2<<<dim3(313, 2), 256, 0, stream>>>(rnn, Wmap, bmap, omap);
  k_wt<<<300, 256, 0, stream>>>(Whh, WhhT);
  k_bucket<<<1, 128, 0, stream>>>(times, bcnt, bucket);

  if (fast)
    k_gemm<false><<<235, 512, GEMM_LDS, stream>>>(A2, B2, Z, nullptr, nullptr,
                                                  nullptr, nullptr, nullptr);
  else
    k_passA<<<NBLK_V, 256, 0, stream>>>(wemb, A2, Z);

  k_igemm<<<400, 256, 0, stream>>>(Wih, bihp, bhhp, omap, Gin, 0);
  k_rec<<<1, 1024, 0, stream>>>(WhhT, Gin, xa);
  k_igemm<<<400, 256, 0, stream>>>(Wih, bihp, bhhp, xa, Gin, 1);
  k_rec<<<1, 1024, 0, stream>>>(WhhT + 100 * 800, Gin, xb);
  k_igemm<<<400, 256, 0, stream>>>(Wih, bihp, bhhp, xb, Gin, 2);
  k_rec<<<1, 1024, 0, stream>>>(WhhT + 200 * 800, Gin, lout);

  k_eta_pre<<<40, 256, 0, stream>>>(Wme, bme, Wle, ble, lout, mhlh);
  k_eta_chain<<<1, 64, 0, stream>>>(Wme, Wle, mhlh, etas, scal);
  k_hpre<<<dim3(13, 47), 256, 0, stream>>>(nbows, Wth, hpre);
  k_theta<<<100, 256, 0, stream>>>(hpre, bth, Wth, Wmt, bmt, Wlt, blt, etas, times, theta, scal);
  k_wgt<<<25, 256, 0, stream>>>(theta, Z, times, wgt);
  k_klalpha<<<2344, 256, 0, stream>>>(mua, lsa, scal);

  if (fast)
    k_gemm<true><<<235, 512, GEMM_LDS, stream>>>(A2, B2, Z, wgt, bows, bcnt,
                                                 bucket, scal);
  else
    k_passB<<<NBLK_V, 256, 0, stream>>>(wemb, A2, wgt, bows, bcnt, bucket, scal);

  k_finalize<<<1, 64, 0, stream>>>(scal, (float*)d_out);
}